// Round 14
// baseline (179.941 us; speedup 1.0000x reference)
//
#include <hip/hip_runtime.h>
#include <math.h>

typedef __bf16 bf16;
typedef bf16 bf16x8 __attribute__((ext_vector_type(8)));
typedef bf16 bf16x4 __attribute__((ext_vector_type(4)));
typedef float f32x4 __attribute__((ext_vector_type(4)));

constexpr int kB = 8, kC = 512, kC4 = 128, kN = 2048;

#define MFMA16(a, b, c) __builtin_amdgcn_mfma_f32_16x16x32_bf16(a, b, c, 0, 0, 0)

// ---------------------------------------------------------------- prep
__global__ __launch_bounds__(256) void k_prep(
    const int* __restrict__ mask, const float* __restrict__ wqk,
    const float* __restrict__ wv, const float* __restrict__ wt,
    const float* __restrict__ gamma, const float* __restrict__ rvar,
    float* __restrict__ cnt, bf16* __restrict__ wqk_bf,
    bf16* __restrict__ wv_bf, bf16* __restrict__ wt_bf,
    float* __restrict__ invg, float* __restrict__ Ssum) {
  const int t = threadIdx.x;
  if (blockIdx.x < 8) {
    const int b = blockIdx.x;
    int s = 0;
    for (int i = t; i < kN; i += 256) s += mask[b * kN + i];
    __shared__ int red[256];
    red[t] = s;
    __syncthreads();
    for (int off = 128; off > 0; off >>= 1) {
      if (t < off) red[t] += red[t + off];
      __syncthreads();
    }
    if (t == 0) cnt[b] = (float)red[0];
    return;
  }
  const int total = 65536 + 262144 + 262144 + 512 + 16384;
  for (int i = (blockIdx.x - 8) * 256 + t; i < total; i += 128 * 256) {
    if (i < 65536) {
      wqk_bf[i] = (bf16)wqk[i];
    } else if (i < 327680) {
      wv_bf[i - 65536] = (bf16)wv[i - 65536];
    } else if (i < 589824) {
      wt_bf[i - 327680] = (bf16)wt[i - 327680];
    } else if (i < 590336) {
      const int j = i - 589824;
      invg[j] = gamma[j] * rsqrtf(rvar[j] + 1e-5f);
    } else {
      Ssum[i - 590336] = 0.0f;
    }
  }
}

// ---------------- transpose+convert both inputs: [C][N] f32 -> [N][C] bf16
__global__ __launch_bounds__(256) void k_tr2(const float* __restrict__ Q,
                                             const float* __restrict__ X,
                                             bf16* __restrict__ XTq,
                                             bf16* __restrict__ XTx) {
  __shared__ float tile[32][69];
  const int z = blockIdx.z, b = z & 7;
  const float* Xs = (z < 8) ? Q : X;
  bf16* XT = (z < 8) ? XTq : XTx;
  const int c0 = blockIdx.y * 32, n0 = blockIdx.x * 64;
  const int t = threadIdx.x;
  const int cc = t >> 4, n4 = (t & 15) * 4;
#pragma unroll
  for (int p = 0; p < 2; p++) {
    const int c = p * 16 + cc;
    const f32x4 v =
        *(const f32x4*)&Xs[((size_t)(b * kC + c0 + c)) * kN + n0 + n4];
    tile[c][n4 + 0] = v[0];
    tile[c][n4 + 1] = v[1];
    tile[c][n4 + 2] = v[2];
    tile[c][n4 + 3] = v[3];
  }
  __syncthreads();
  const int n = t >> 2, c8 = (t & 3) * 8;
  bf16x8 o;
#pragma unroll
  for (int j = 0; j < 8; j++) o[j] = (bf16)tile[c8 + j][n];
  *(bf16x8*)&XT[((size_t)(b * kN + n0 + n)) * kC + c0 + c8] = o;
}

// -------- q/k projections (staged GEMM): OT[b][n][128] = (wqk @ src)^T
__global__ __launch_bounds__(256, 2) void k_projQK(
    const bf16* __restrict__ XTq, const bf16* __restrict__ XTx,
    const bf16* __restrict__ W, bf16* __restrict__ qT, bf16* __restrict__ kT) {
  __shared__ __align__(16) bf16 As[2][128][32];
  __shared__ __align__(16) bf16 Bs[2][128][32];
  const int nb = blockIdx.x, b = blockIdx.y, src = blockIdx.z;
  const bf16* XT = src ? XTx : XTq;
  bf16* OT = src ? kT : qT;
  const int n0 = nb * 128;
  const int t_ = threadIdx.x, w = t_ >> 6, l = t_ & 63, lo4 = l & 15, g = l >> 4;
  const int mh = w >> 1, ch = w & 1;
  const int srow = w * 16 + (l >> 2), sch = l & 3;
  const int spos = sch ^ ((l >> 3) & 3);
  const int rpos = g ^ ((lo4 >> 1) & 3);
  const bf16* gA0 = &XT[((size_t)(b * kN + n0 + srow)) * kC + sch * 8];
  const bf16* gA1 = gA0 + (size_t)64 * kC;
  const bf16* gB0 = &W[(size_t)srow * kC + sch * 8];
  const bf16* gB1 = gB0 + (size_t)64 * kC;
  f32x4 acc[4][4] = {};
  bf16x8 ra0, ra1, rb0, rb1;
  ra0 = *(const bf16x8*)&gA0[0];
  ra1 = *(const bf16x8*)&gA1[0];
  rb0 = *(const bf16x8*)&gB0[0];
  rb1 = *(const bf16x8*)&gB1[0];
  *(bf16x8*)&As[0][srow][spos * 8] = ra0;
  *(bf16x8*)&As[0][srow + 64][spos * 8] = ra1;
  *(bf16x8*)&Bs[0][srow][spos * 8] = rb0;
  *(bf16x8*)&Bs[0][srow + 64][spos * 8] = rb1;
  __syncthreads();
  for (int tt = 0; tt < 16; tt++) {
    const int buf = tt & 1;
    if (tt < 15) {
      const int k0 = (tt + 1) * 32;
      ra0 = *(const bf16x8*)&gA0[k0];
      ra1 = *(const bf16x8*)&gA1[k0];
      rb0 = *(const bf16x8*)&gB0[k0];
      rb1 = *(const bf16x8*)&gB1[k0];
    }
    bf16x8 af[4], bfr[4];
#pragma unroll
    for (int nf = 0; nf < 4; nf++)
      af[nf] = *(const bf16x8*)&As[buf][mh * 64 + nf * 16 + lo4][rpos * 8];
#pragma unroll
    for (int cf = 0; cf < 4; cf++)
      bfr[cf] = *(const bf16x8*)&Bs[buf][ch * 64 + cf * 16 + lo4][rpos * 8];
#pragma unroll
    for (int nf = 0; nf < 4; nf++)
#pragma unroll
      for (int cf = 0; cf < 4; cf++)
        acc[nf][cf] = MFMA16(af[nf], bfr[cf], acc[nf][cf]);
    if (tt < 15) {
      *(bf16x8*)&As[buf ^ 1][srow][spos * 8] = ra0;
      *(bf16x8*)&As[buf ^ 1][srow + 64][spos * 8] = ra1;
      *(bf16x8*)&Bs[buf ^ 1][srow][spos * 8] = rb0;
      *(bf16x8*)&Bs[buf ^ 1][srow + 64][spos * 8] = rb1;
    }
    __syncthreads();
  }
  bf16* bncw = ((bf16*)As) + w * 16 * 72;
#pragma unroll
  for (int nf = 0; nf < 4; nf++) {
    const int nbase = n0 + mh * 64 + nf * 16;
#pragma unroll
    for (int cf = 0; cf < 4; cf++)
#pragma unroll
      for (int r = 0; r < 4; r++)
        bncw[(4 * g + r) * 72 + cf * 16 + lo4] = (bf16)acc[nf][cf][r];
    const int rr = l >> 2, seg = (l & 3) * 16;
    const bf16x8 v0 = *(const bf16x8*)&bncw[rr * 72 + seg];
    const bf16x8 v1 = *(const bf16x8*)&bncw[rr * 72 + seg + 8];
    bf16* orow = &OT[((size_t)(b * kN + nbase + rr)) * kC4 + ch * 64 + seg];
    *(bf16x8*)&orow[0] = v0;
    *(bf16x8*)&orow[8] = v1;
  }
}

// -------- value projection (staged GEMM) -> TILED xv2[b][n>>6][c][n&63]
__global__ __launch_bounds__(256, 2) void k_projV(
    const bf16* __restrict__ XTx, const bf16* __restrict__ Wv,
    const float* __restrict__ bv, bf16* __restrict__ xv2) {
  __shared__ __align__(16) bf16 As[2][128][32];
  __shared__ __align__(16) bf16 Bs[2][128][32];
  const int blk = blockIdx.x;  // 512 = 8b x (16nb x 4cb)
  const int b = blk & 7, tile = blk >> 3;
  const int cb = tile & 3, nb = tile >> 2;
  const int n0 = nb * 128, c0 = cb * 128;
  const int t_ = threadIdx.x, w = t_ >> 6, l = t_ & 63, lo4 = l & 15, g = l >> 4;
  const int mh = w >> 1, ch = w & 1;
  const int srow = w * 16 + (l >> 2), sch = l & 3;
  const int spos = sch ^ ((l >> 3) & 3);
  const int rpos = g ^ ((lo4 >> 1) & 3);
  const bf16* gA0 = &XTx[((size_t)(b * kN + n0 + srow)) * kC + sch * 8];
  const bf16* gA1 = gA0 + (size_t)64 * kC;
  const bf16* gB0 = &Wv[(size_t)(c0 + srow) * kC + sch * 8];
  const bf16* gB1 = gB0 + (size_t)64 * kC;
  f32x4 acc[4][4] = {};
  bf16x8 ra0, ra1, rb0, rb1;
  ra0 = *(const bf16x8*)&gA0[0];
  ra1 = *(const bf16x8*)&gA1[0];
  rb0 = *(const bf16x8*)&gB0[0];
  rb1 = *(const bf16x8*)&gB1[0];
  *(bf16x8*)&As[0][srow][spos * 8] = ra0;
  *(bf16x8*)&As[0][srow + 64][spos * 8] = ra1;
  *(bf16x8*)&Bs[0][srow][spos * 8] = rb0;
  *(bf16x8*)&Bs[0][srow + 64][spos * 8] = rb1;
  __syncthreads();
  for (int tt = 0; tt < 16; tt++) {
    const int buf = tt & 1;
    if (tt < 15) {
      const int k0 = (tt + 1) * 32;
      ra0 = *(const bf16x8*)&gA0[k0];
      ra1 = *(const bf16x8*)&gA1[k0];
      rb0 = *(const bf16x8*)&gB0[k0];
      rb1 = *(const bf16x8*)&gB1[k0];
    }
    bf16x8 af[4], bfr[4];
#pragma unroll
    for (int nf = 0; nf < 4; nf++)
      af[nf] = *(const bf16x8*)&As[buf][mh * 64 + nf * 16 + lo4][rpos * 8];
#pragma unroll
    for (int cf = 0; cf < 4; cf++)
      bfr[cf] = *(const bf16x8*)&Bs[buf][ch * 64 + cf * 16 + lo4][rpos * 8];
#pragma unroll
    for (int nf = 0; nf < 4; nf++)
#pragma unroll
      for (int cf = 0; cf < 4; cf++)
        acc[nf][cf] = MFMA16(af[nf], bfr[cf], acc[nf][cf]);
    if (tt < 15) {
      *(bf16x8*)&As[buf ^ 1][srow][spos * 8] = ra0;
      *(bf16x8*)&As[buf ^ 1][srow + 64][spos * 8] = ra1;
      *(bf16x8*)&Bs[buf ^ 1][srow][spos * 8] = rb0;
      *(bf16x8*)&Bs[buf ^ 1][srow + 64][spos * 8] = rb1;
    }
    __syncthreads();
  }
#pragma unroll
  for (int cf = 0; cf < 4; cf++) {
    const int c = c0 + ch * 64 + cf * 16 + lo4;
    const float bvv = bv[c];
#pragma unroll
    for (int nf = 0; nf < 4; nf++) {
      const int nbase = n0 + mh * 64 + nf * 16 + g * 4;
      bf16x4 o;
#pragma unroll
      for (int r = 0; r < 4; r++) o[r] = (bf16)(acc[nf][cf][r] + bvv);
      *(bf16x4*)&xv2[(((size_t)b * 32 + (nbase >> 6)) * kC + c) * 64 +
                     (nbase & 63)] = o;
    }
  }
}

// ---------------- pass 1: U^T[m][n] exp-factors; COALESCED stores via LDS
// transpose (XOR-swizzled 8B units); partial S[n] via atomics.
__global__ __launch_bounds__(256) void k_sum(
    const bf16* __restrict__ qT, const bf16* __restrict__ kT,
    const int* __restrict__ mask, const float* __restrict__ cnt,
    bf16* __restrict__ UT, float* __restrict__ Ssum) {
  __shared__ __align__(16) bf16 kts[2][64][128];
  __shared__ __align__(16) bf16 Ubuf[64][64];
  __shared__ int mss[2][64];
  const int blk = blockIdx.x;
  const int b = blk & 7, nb = (blk >> 3) & 31, mh2 = blk >> 8;
  const int m00 = mh2 * 1024;
  const int t_ = threadIdx.x, w = t_ >> 6, l = t_ & 63, lo4 = l & 15, g = l >> 4;
  const float invd = 1.0f / (cnt[b] + 1e-9f);
  const int n0 = nb * 64;
  bf16x8 aq[4];
#pragma unroll
  for (int ks = 0; ks < 4; ks++)
    aq[ks] = *(const bf16x8*)&qT[((size_t)(b * kN + n0 + w * 16 + lo4)) * kC4 +
                                 ks * 32 + g * 8];
  const int nq = n0 + w * 16 + g * 4;
  const int4 mi = *(const int4*)&mask[b * kN + nq];
  const int mn4[4] = {mi.x, mi.y, mi.z, mi.w};
  float rs4[4] = {0.0f, 0.0f, 0.0f, 0.0f};
  bf16x8 rg[4];
#pragma unroll
  for (int i = 0; i < 4; i++) {
    const int row = w * 16 + i * 4 + g;
    const int q = (l & 15) ^ (row & 7);
    rg[i] = *(const bf16x8*)&kT[((size_t)(b * kN + m00 + row)) * kC4 + q * 8];
  }
#pragma unroll
  for (int i = 0; i < 4; i++) {
    const int row = w * 16 + i * 4 + g;
    *(bf16x8*)&kts[0][row][(l & 15) * 8] = rg[i];
  }
  if (t_ < 16)
    *(int4*)&mss[0][t_ * 4] = *(const int4*)&mask[b * kN + m00 + t_ * 4];
  __syncthreads();
  for (int tt = 0; tt < 16; tt++) {
    const int buf = tt & 1;
    if (tt < 15) {
      const int m0 = m00 + (tt + 1) * 64;
#pragma unroll
      for (int i = 0; i < 4; i++) {
        const int row = w * 16 + i * 4 + g;
        const int q = (l & 15) ^ (row & 7);
        rg[i] = *(const bf16x8*)&kT[((size_t)(b * kN + m0 + row)) * kC4 + q * 8];
      }
    }
#pragma unroll
    for (int mf = 0; mf < 4; mf++) {
      f32x4 e = {};
#pragma unroll
      for (int ks = 0; ks < 4; ks++) {
        const bf16x8 bk =
            *(const bf16x8*)&kts[buf][mf * 16 + lo4]
                                 [((ks * 4 + g) ^ (lo4 & 7)) * 8];
        e = MFMA16(aq[ks], bk, e);
      }
      const int mmv = mss[buf][mf * 16 + lo4];
      bf16x4 pk;
#pragma unroll
      for (int r = 0; r < 4; r++) {
        const float u = mmv ? (mn4[r] ? __expf(e[r] * invd) : 1.0f) : 0.0f;
        pk[r] = (bf16)u;
        rs4[r] += (float)pk[r];
      }
      // swizzled LDS write: row=mf*16+lo4, unit u=w*4+g, pos=u^lo4
      *(bf16x4*)&Ubuf[mf * 16 + lo4][((w * 4 + g) ^ lo4) * 4] = pk;
    }
    __syncthreads();
    // phase 2: stage next kts + coalesced UT store from Ubuf
    if (tt < 15) {
#pragma unroll
      for (int i = 0; i < 4; i++) {
        const int row = w * 16 + i * 4 + g;
        *(bf16x8*)&kts[buf ^ 1][row][(l & 15) * 8] = rg[i];
      }
      if (t_ < 16)
        *(int4*)&mss[buf ^ 1][t_ * 4] =
            *(const int4*)&mask[b * kN + m00 + (tt + 1) * 64 + t_ * 4];
    }
    {
      const int row = t_ >> 2, q = t_ & 3;
      bf16x4 seg[4];
#pragma unroll
      for (int k = 0; k < 4; k++) {
        const int us = q * 4 + k;
        seg[k] = *(const bf16x4*)&Ubuf[row][(us ^ (row & 15)) * 4];
      }
      bf16x8 s0, s1;
#pragma unroll
      for (int j = 0; j < 4; j++) {
        s0[j] = seg[0][j];
        s0[4 + j] = seg[1][j];
        s1[j] = seg[2][j];
        s1[4 + j] = seg[3][j];
      }
      bf16* orow =
          &UT[((size_t)(b * kN + m00 + tt * 64 + row)) * kN + n0 + q * 16];
      *(bf16x8*)&orow[0] = s0;
      *(bf16x8*)&orow[8] = s1;
    }
    __syncthreads();
  }
#pragma unroll
  for (int r = 0; r < 4; r++) {
#pragma unroll
    for (int off = 1; off < 16; off <<= 1) rs4[r] += __shfl_xor(rs4[r], off);
  }
  if (lo4 == 0) {
#pragma unroll
    for (int r = 0; r < 4; r++) atomicAdd(&Ssum[b * kN + nq + r], rs4[r]);
  }
}

// ---------------- Ssum -> 1/Ssum in place
__global__ __launch_bounds__(256) void k_invs(float* __restrict__ Ssum) {
  const int i = blockIdx.x * 256 + threadIdx.x;
  Ssum[i] = 1.0f / Ssum[i];
}

// -------- pass 2: x_r^T[m][c] = sum_n UT[m][n]*(xv2[c][n]*invS[n]); h=x-x_r
// 64m x 128c blocks, 4 waves, 4 blocks/CU (grid 1024), depth-2 reg pipeline.
__global__ __launch_bounds__(256, 4) void k_attn2(
    const bf16* __restrict__ UT, const bf16* __restrict__ xv2,
    const float* __restrict__ invS, const float* __restrict__ x,
    bf16* __restrict__ hT) {
  __shared__ __align__(16) bf16 As[2][64][32];
  __shared__ __align__(16) bf16 Bs[2][128][32];
  const int blk = blockIdx.x;  // 1024 = 8b x (32mb x 4cb)
  const int b = blk & 7, tile = blk >> 3;
  const int cb = tile & 3, mb = tile >> 2;
  const int m0 = mb * 64, c0 = cb * 128;
  const int t_ = threadIdx.x, w = t_ >> 6, l = t_ & 63, lo4 = l & 15, g = l >> 4;
  const int mh = w >> 1, ch = w & 1;
  const int srow = t_ >> 2, sch = t_ & 3;
  const int spos = sch ^ ((srow >> 1) & 3);
  const int rpos = g ^ ((lo4 >> 1) & 3);
  const bf16* gA = &UT[((size_t)(b * kN + m0 + srow)) * kN + sch * 8];
  const bf16* gB0 = &xv2[(((size_t)b * 32) * kC + c0 + srow) * 64 + sch * 8];
  const bf16* gB1 = gB0 + (size_t)64 * 64;
  const float* isB = &invS[b * kN];
  f32x4 acc[2][4] = {};
#define SCALE8(v, s0, s1, o)                                                   \
  _Pragma("unroll") for (int j = 0; j < 4; j++) {                              \
    o[j] = (bf16)((float)v[j] * s0[j]);                                        \
    o[4 + j] = (bf16)((float)v[4 + j] * s1[j]);                                \
  }
  // prologue: iter0 direct; iter1 pending
  {
    const bf16x8 a = *(const bf16x8*)&gA[0];
    const bf16x8 b0 = *(const bf16x8*)&gB0[0];
    const bf16x8 b1 = *(const bf16x8*)&gB1[0];
    const f32x4 s0 = *(const f32x4*)&isB[sch * 8];
    const f32x4 s1 = *(const f32x4*)&isB[sch * 8 + 4];
    bf16x8 o0, o1;
    SCALE8(b0, s0, s1, o0);
    SCALE8(b1, s0, s1, o1);
    *(bf16x8*)&As[0][srow][spos * 8] = a;
    *(bf16x8*)&Bs[0][srow][spos * 8] = o0;
    *(bf16x8*)&Bs[0][srow + 64][spos * 8] = o1;
  }
  bf16x8 oA, oB0, oB1, eA, eB0, eB1;
  f32x4 oS0, oS1, eS0, eS1;
  oA = *(const bf16x8*)&gA[32];
  oB0 = *(const bf16x8*)&gB0[32];
  oB1 = *(const bf16x8*)&gB1[32];
  oS0 = *(const f32x4*)&isB[32 + sch * 8];
  oS1 = *(const f32x4*)&isB[32 + sch * 8 + 4];
  __syncthreads();
#define FRAGS_MFMA(BUF)                                                        \
  {                                                                            \
    bf16x8 af[2], bfr[4];                                                      \
    _Pragma("unroll") for (int mf = 0; mf < 2; mf++) af[mf] =                  \
        *(const bf16x8*)&As[BUF][mh * 32 + mf * 16 + lo4][rpos * 8];           \
    _Pragma("unroll") for (int cf = 0; cf < 4; cf++) bfr[cf] =                 \
        *(const bf16x8*)&Bs[BUF][ch * 64 + cf * 16 + lo4][rpos * 8];           \
    _Pragma("unroll") for (int mf = 0; mf < 2; mf++)                           \
        _Pragma("unroll") for (int cf = 0; cf < 4; cf++) acc[mf][cf] =         \
            MFMA16(af[mf], bfr[cf], acc[mf][cf]);                              \
  }
  for (int tt2 = 0; tt2 < 64; tt2 += 2) {
    if (tt2 + 2 < 64) {
      const int n2 = tt2 + 2;
      eA = *(const bf16x8*)&gA[n2 * 32];
      const size_t bo = (size_t)(n2 >> 1) * (kC * 64) + (n2 & 1) * 32;
      eB0 = *(const bf16x8*)&gB0[bo];
      eB1 = *(const bf16x8*)&gB1[bo];
      eS0 = *(const f32x4*)&isB[n2 * 32 + sch * 8];
      eS1 = *(const f32x4*)&isB[n2 * 32 + sch * 8 + 4];
    }
    FRAGS_MFMA(0);
    {
      bf16x8 o0, o1;
      SCALE8(oB0, oS0, oS1, o0);
      SCALE8(oB1, oS0, oS1, o1);
      *(bf16x8*)&As[1][srow][spos * 8] = oA;
      *(bf16x8*)&Bs[1][srow][spos * 8] = o0;
      *(bf16x8*)&Bs[1][srow + 64][spos * 8] = o1;
    }
    __syncthreads();
    if (tt2 + 3 < 64) {
      const int n3 = tt2 + 3;
      oA = *(const bf16x8*)&gA[n3 * 32];
      const size_t bo = (size_t)(n3 >> 1) * (kC * 64) + (n3 & 1) * 32;
      oB0 = *(const bf16x8*)&gB0[bo];
      oB1 = *(const bf16x8*)&gB1[bo];
      oS0 = *(const f32x4*)&isB[n3 * 32 + sch * 8];
      oS1 = *(const f32x4*)&isB[n3 * 32 + sch * 8 + 4];
    }
    FRAGS_MFMA(1);
    if (tt2 + 2 < 64) {
      bf16x8 o0, o1;
      SCALE8(eB0, eS0, eS1, o0);
      SCALE8(eB1, eS0, eS1, o1);
      *(bf16x8*)&As[0][srow][spos * 8] = eA;
      *(bf16x8*)&Bs[0][srow][spos * 8] = o0;
      *(bf16x8*)&Bs[0][srow + 64][spos * 8] = o1;
    }
    __syncthreads();
  }
#undef FRAGS_MFMA
#undef SCALE8
  // epilogue: h = x - x_r; per-wave LDS transpose (in Bs) -> hT[m][c]
  bf16* bncw = ((bf16*)Bs) + w * 16 * 72;
#pragma unroll
  for (int mf = 0; mf < 2; mf++) {
    const int mbase = m0 + mh * 32 + mf * 16;
    float hh[4][4];
#pragma unroll
    for (int cf = 0; cf < 4; cf++) {
      const int c = c0 + ch * 64 + cf * 16 + lo4;
      const f32x4 xval =
          *(const f32x4*)&x[((size_t)(b * kC + c)) * kN + mbase + g * 4];
#pragma unroll
      for (int r = 0; r < 4; r++) hh[cf][r] = xval[r] - acc[mf][cf][r];
    }
#pragma unroll
    for (int cf = 0; cf < 4; cf++)
#pragma unroll
      for (int r = 0; r < 4; r++)
        bncw[(4 * g + r) * 72 + cf * 16 + lo4] = (bf16)hh[cf][r];
    {
      const int rr = l >> 2, seg = (l & 3) * 16;
      const bf16x8 v0 = *(const bf16x8*)&bncw[rr * 72 + seg];
      const bf16x8 v1 = *(const bf16x8*)&bncw[rr * 72 + seg + 8];
      bf16* orow =
          &hT[((size_t)(b * kN + mbase + rr)) * kC + c0 + ch * 64 + seg];
      *(bf16x8*)&orow[0] = v0;
      *(bf16x8*)&orow[8] = v1;
    }
    __syncthreads();
  }
}

// -------- final: D[n][c] = hT[n][k] wt[c][k]; BN+ReLU+residual
__global__ __launch_bounds__(256, 2) void k_final(
    const bf16* __restrict__ hT, const bf16* __restrict__ wt_bf,
    const float* __restrict__ x, const float* __restrict__ bt,
    const float* __restrict__ beta, const float* __restrict__ rmean,
    const float* __restrict__ invg, float* __restrict__ out) {
  __shared__ __align__(16) bf16 As[2][128][32];
  __shared__ __align__(16) bf16 Bs[2][128][32];
  const int blk = blockIdx.x;  // 512 = 8b x (16nb x 4cb)
  const int b = blk & 7, tile = blk >> 3;
  const int cb = tile & 3, nb = tile >> 2;
  const int n0 = nb * 128, c0 = cb * 128;
  const int t_ = threadIdx.x, w = t_ >> 6, l = t_ & 63, lo4 = l & 15, g = l >> 4;
  const int mh = w >> 1, ch = w & 1;
  const int srow = w * 16 + (l >> 2), sch = l & 3;
  const int spos = sch ^ ((l >> 3) & 3);
  const int rpos = g ^ ((lo4 >> 1) & 3);
  const bf16* gA0 = &hT[((size_t)(b * kN + n0 + srow)) * kC + sch * 8];
  const bf16* gA1 = gA0 + (size_t)64 * kC;
  const bf16* gB0 = &wt_bf[(size_t)(c0 + srow) * kC + sch * 8];
  const bf16* gB1 = gB0 + (size_t)64 * kC;
  f32x4 acc[4][4] = {};
  bf16x8 ra0, ra1, rb0, rb1;
  ra0 = *(const bf16x8*)&gA0[0];
  ra1 = *(const bf16x8*)&gA1[0];
  rb0 = *(const bf16x8*)&gB0[0];
  rb1 = *(const bf16x8*)&gB1[0];
  *(bf16x8*)&As[0][srow][spos * 8] = ra0;
  *(bf16x8*)&As[0][srow + 64][spos * 8] = ra1;
  *(bf16x8*)&Bs[0][srow][spos * 8] = rb0;
  *(bf16x8*)&Bs[0][srow + 64][spos * 8] = rb1;
  __syncthreads();
  for (int tt = 0; tt < 16; tt++) {
    const int buf = tt & 1;
    if (tt < 15) {
      const int k0 = (tt + 1) * 32;
      ra0 = *(const bf16x8*)&gA0[k0];
      ra1 = *(const bf16x8*)&gA1[k0];
      rb0 = *(const bf16x8*)&gB0[k0];
      rb1 = *(const bf16x8*)&gB1[k0];
    }
    bf16x8 af[4], bfr[4];
#pragma unroll
    for (int nf = 0; nf < 4; nf++)
      af[nf] = *(const bf16x8*)&As[buf][mh * 64 + nf * 16 + lo4][rpos * 8];
#pragma unroll
    for (int cf = 0; cf < 4; cf++)
      bfr[cf] = *(const bf16x8*)&Bs[buf][ch * 64 + cf * 16 + lo4][rpos * 8];
#pragma unroll
    for (int nf = 0; nf < 4; nf++)
#pragma unroll
      for (int cf = 0; cf < 4; cf++)
        acc[nf][cf] = MFMA16(af[nf], bfr[cf], acc[nf][cf]);
    if (tt < 15) {
      *(bf16x8*)&As[buf ^ 1][srow][spos * 8] = ra0;
      *(bf16x8*)&As[buf ^ 1][srow + 64][spos * 8] = ra1;
      *(bf16x8*)&Bs[buf ^ 1][srow][spos * 8] = rb0;
      *(bf16x8*)&Bs[buf ^ 1][srow + 64][spos * 8] = rb1;
    }
    __syncthreads();
  }
#pragma unroll
  for (int cf = 0; cf < 4; cf++) {
    const int c = c0 + ch * 64 + cf * 16 + lo4;
    const float btv = bt[c], rmv = rmean[c], igv = invg[c], bev = beta[c];
#pragma unroll
    for (int nf = 0; nf < 4; nf++) {
      const int nbase = n0 + mh * 64 + nf * 16 + g * 4;
      const size_t base = ((size_t)(b * kC + c)) * kN + nbase;
      const f32x4 xval = *(const f32x4*)&x[base];
      f32x4 o;
#pragma unroll
      for (int r = 0; r < 4; r++) {
        float v = (acc[nf][cf][r] + btv - rmv) * igv + bev;
        v = fmaxf(v, 0.0f);
        o[r] = xval[r] + v;
      }
      *(f32x4*)&out[base] = o;
    }
  }
}

extern "C" void kernel_launch(void* const* d_in, const int* in_sizes, int n_in,
                              void* d_out, int out_size, void* d_ws,
                              size_t ws_size, hipStream_t stream) {
  const float* x = (const float*)d_in[0];
  const float* query = (const float*)d_in[1];
  const int* mask = (const int*)d_in[2];
  const float* wqk = (const float*)d_in[3];
  const float* wv = (const float*)d_in[4];
  const float* bv = (const float*)d_in[5];
  const float* wt = (const float*)d_in[6];
  const float* bt = (const float*)d_in[7];
  const float* gamma = (const float*)d_in[8];
  const float* beta = (const float*)d_in[9];
  const float* rmean = (const float*)d_in[10];
  const float* rvar = (const float*)d_in[11];
  float* out = (float*)d_out;
  char* wsb = (char*)d_ws;

  const size_t MB = 1024 * 1024;
  bf16* UT = (bf16*)wsb;                        // 64 MB [b][m][n]
  bf16* trbufQ = (bf16*)wsb;                    // 16 MB (in UT dead zone)
  bf16* trbufX = (bf16*)(wsb + 16 * MB);        // 16 MB (in UT dead zone)
  bf16* xv2 = (bf16*)(wsb + 64 * MB);           // 16 MB tiled
  bf16* hT = (bf16*)(wsb + 80 * MB);            // 8 MB [b][n][c]
  bf16* qT = (bf16*)(wsb + 88 * MB);            // 4 MB
  bf16* kT = (bf16*)(wsb + 92 * MB);            // 4 MB
  bf16* wqk_bf = (bf16*)(wsb + 96 * MB);        // 128 KB
  bf16* wv_bf = wqk_bf + 65536;                 // 512 KB
  bf16* wt_bf = wv_bf + 262144;                 // 512 KB
  float* invg = (float*)(wt_bf + 262144);       // 2 KB
  float* Ssum = invg + 512;                     // 64 KB (becomes invS)
  float* cnt = Ssum + kB * kN;                  // 32 B

  k_prep<<<136, 256, 0, stream>>>(mask, wqk, wv, wt, gamma, rvar, cnt, wqk_bf,
                                  wv_bf, wt_bf, invg, Ssum);
  k_tr2<<<dim3(kN / 64, kC / 32, 16), 256, 0, stream>>>(query, x, trbufQ,
                                                        trbufX);
  k_projQK<<<dim3(16, kB, 2), 256, 0, stream>>>(trbufQ, trbufX, wqk_bf, qT,
                                                kT);
  k_projV<<<512, 256, 0, stream>>>(trbufX, wv_bf, bv, xv2);
  k_sum<<<512, 256, 0, stream>>>(qT, kT, mask, cnt, UT, Ssum);
  k_invs<<<64, 256, 0, stream>>>(Ssum);
  k_attn2<<<1024, 256, 0, stream>>>(UT, xv2, Ssum, x, hT);
  k_final<<<512, 256, 0, stream>>>(hT, wt_bf, x, bt, beta, rmean, invg, out);
}

// Round 15
// 163.617 us; speedup vs baseline: 1.0998x; 1.0998x over previous
//
#include <hip/hip_runtime.h>
#include <math.h>

typedef __bf16 bf16;
typedef bf16 bf16x8 __attribute__((ext_vector_type(8)));
typedef bf16 bf16x4 __attribute__((ext_vector_type(4)));
typedef float f32x4 __attribute__((ext_vector_type(4)));

constexpr int kB = 8, kC = 512, kC4 = 128, kN = 2048;

#define MFMA16(a, b, c) __builtin_amdgcn_mfma_f32_16x16x32_bf16(a, b, c, 0, 0, 0)

// ---------------------------------------------------------------- prep
__global__ __launch_bounds__(256) void k_prep(
    const int* __restrict__ mask, const float* __restrict__ wqk,
    const float* __restrict__ wv, const float* __restrict__ wt,
    const float* __restrict__ gamma, const float* __restrict__ rvar,
    float* __restrict__ cnt, bf16* __restrict__ wqk_bf,
    bf16* __restrict__ wv_bf, bf16* __restrict__ wt_bf,
    float* __restrict__ invg, float* __restrict__ Ssum) {
  const int t = threadIdx.x;
  if (blockIdx.x < 8) {
    const int b = blockIdx.x;
    int s = 0;
    for (int i = t; i < kN; i += 256) s += mask[b * kN + i];
    __shared__ int red[256];
    red[t] = s;
    __syncthreads();
    for (int off = 128; off > 0; off >>= 1) {
      if (t < off) red[t] += red[t + off];
      __syncthreads();
    }
    if (t == 0) cnt[b] = (float)red[0];
    return;
  }
  const int total = 65536 + 262144 + 262144 + 512 + 16384;
  for (int i = (blockIdx.x - 8) * 256 + t; i < total; i += 128 * 256) {
    if (i < 65536) {
      wqk_bf[i] = (bf16)wqk[i];
    } else if (i < 327680) {
      wv_bf[i - 65536] = (bf16)wv[i - 65536];
    } else if (i < 589824) {
      wt_bf[i - 327680] = (bf16)wt[i - 327680];
    } else if (i < 590336) {
      const int j = i - 589824;
      invg[j] = gamma[j] * rsqrtf(rvar[j] + 1e-5f);
    } else {
      Ssum[i - 590336] = 0.0f;
    }
  }
}

// ---------------- transpose+convert both inputs: [C][N] f32 -> [N][C] bf16
__global__ __launch_bounds__(256) void k_tr2(const float* __restrict__ Q,
                                             const float* __restrict__ X,
                                             bf16* __restrict__ XTq,
                                             bf16* __restrict__ XTx) {
  __shared__ float tile[32][69];
  const int z = blockIdx.z, b = z & 7;
  const float* Xs = (z < 8) ? Q : X;
  bf16* XT = (z < 8) ? XTq : XTx;
  const int c0 = blockIdx.y * 32, n0 = blockIdx.x * 64;
  const int t = threadIdx.x;
  const int cc = t >> 4, n4 = (t & 15) * 4;
#pragma unroll
  for (int p = 0; p < 2; p++) {
    const int c = p * 16 + cc;
    const f32x4 v =
        *(const f32x4*)&Xs[((size_t)(b * kC + c0 + c)) * kN + n0 + n4];
    tile[c][n4 + 0] = v[0];
    tile[c][n4 + 1] = v[1];
    tile[c][n4 + 2] = v[2];
    tile[c][n4 + 3] = v[3];
  }
  __syncthreads();
  const int n = t >> 2, c8 = (t & 3) * 8;
  bf16x8 o;
#pragma unroll
  for (int j = 0; j < 8; j++) o[j] = (bf16)tile[c8 + j][n];
  *(bf16x8*)&XT[((size_t)(b * kN + n0 + n)) * kC + c0 + c8] = o;
}

// -------- q/k projections (staged GEMM): OT[b][n][128] = (wqk @ src)^T
__global__ __launch_bounds__(256, 2) void k_projQK(
    const bf16* __restrict__ XTq, const bf16* __restrict__ XTx,
    const bf16* __restrict__ W, bf16* __restrict__ qT, bf16* __restrict__ kT) {
  __shared__ __align__(16) bf16 As[2][128][32];
  __shared__ __align__(16) bf16 Bs[2][128][32];
  const int nb = blockIdx.x, b = blockIdx.y, src = blockIdx.z;
  const bf16* XT = src ? XTx : XTq;
  bf16* OT = src ? kT : qT;
  const int n0 = nb * 128;
  const int t_ = threadIdx.x, w = t_ >> 6, l = t_ & 63, lo4 = l & 15, g = l >> 4;
  const int mh = w >> 1, ch = w & 1;
  const int srow = w * 16 + (l >> 2), sch = l & 3;
  const int spos = sch ^ ((l >> 3) & 3);
  const int rpos = g ^ ((lo4 >> 1) & 3);
  const bf16* gA0 = &XT[((size_t)(b * kN + n0 + srow)) * kC + sch * 8];
  const bf16* gA1 = gA0 + (size_t)64 * kC;
  const bf16* gB0 = &W[(size_t)srow * kC + sch * 8];
  const bf16* gB1 = gB0 + (size_t)64 * kC;
  f32x4 acc[4][4] = {};
  bf16x8 ra0, ra1, rb0, rb1;
  ra0 = *(const bf16x8*)&gA0[0];
  ra1 = *(const bf16x8*)&gA1[0];
  rb0 = *(const bf16x8*)&gB0[0];
  rb1 = *(const bf16x8*)&gB1[0];
  *(bf16x8*)&As[0][srow][spos * 8] = ra0;
  *(bf16x8*)&As[0][srow + 64][spos * 8] = ra1;
  *(bf16x8*)&Bs[0][srow][spos * 8] = rb0;
  *(bf16x8*)&Bs[0][srow + 64][spos * 8] = rb1;
  __syncthreads();
  for (int tt = 0; tt < 16; tt++) {
    const int buf = tt & 1;
    if (tt < 15) {
      const int k0 = (tt + 1) * 32;
      ra0 = *(const bf16x8*)&gA0[k0];
      ra1 = *(const bf16x8*)&gA1[k0];
      rb0 = *(const bf16x8*)&gB0[k0];
      rb1 = *(const bf16x8*)&gB1[k0];
    }
    bf16x8 af[4], bfr[4];
#pragma unroll
    for (int nf = 0; nf < 4; nf++)
      af[nf] = *(const bf16x8*)&As[buf][mh * 64 + nf * 16 + lo4][rpos * 8];
#pragma unroll
    for (int cf = 0; cf < 4; cf++)
      bfr[cf] = *(const bf16x8*)&Bs[buf][ch * 64 + cf * 16 + lo4][rpos * 8];
#pragma unroll
    for (int nf = 0; nf < 4; nf++)
#pragma unroll
      for (int cf = 0; cf < 4; cf++)
        acc[nf][cf] = MFMA16(af[nf], bfr[cf], acc[nf][cf]);
    if (tt < 15) {
      *(bf16x8*)&As[buf ^ 1][srow][spos * 8] = ra0;
      *(bf16x8*)&As[buf ^ 1][srow + 64][spos * 8] = ra1;
      *(bf16x8*)&Bs[buf ^ 1][srow][spos * 8] = rb0;
      *(bf16x8*)&Bs[buf ^ 1][srow + 64][spos * 8] = rb1;
    }
    __syncthreads();
  }
  bf16* bncw = ((bf16*)As) + w * 16 * 72;
#pragma unroll
  for (int nf = 0; nf < 4; nf++) {
    const int nbase = n0 + mh * 64 + nf * 16;
#pragma unroll
    for (int cf = 0; cf < 4; cf++)
#pragma unroll
      for (int r = 0; r < 4; r++)
        bncw[(4 * g + r) * 72 + cf * 16 + lo4] = (bf16)acc[nf][cf][r];
    const int rr = l >> 2, seg = (l & 3) * 16;
    const bf16x8 v0 = *(const bf16x8*)&bncw[rr * 72 + seg];
    const bf16x8 v1 = *(const bf16x8*)&bncw[rr * 72 + seg + 8];
    bf16* orow = &OT[((size_t)(b * kN + nbase + rr)) * kC4 + ch * 64 + seg];
    *(bf16x8*)&orow[0] = v0;
    *(bf16x8*)&orow[8] = v1;
  }
}

// -------- value projection (staged GEMM) -> TILED xv2[b][n>>6][c][n&63]
__global__ __launch_bounds__(256, 2) void k_projV(
    const bf16* __restrict__ XTx, const bf16* __restrict__ Wv,
    const float* __restrict__ bv, bf16* __restrict__ xv2) {
  __shared__ __align__(16) bf16 As[2][128][32];
  __shared__ __align__(16) bf16 Bs[2][128][32];
  const int blk = blockIdx.x;  // 512 = 8b x (16nb x 4cb)
  const int b = blk & 7, tile = blk >> 3;
  const int cb = tile & 3, nb = tile >> 2;
  const int n0 = nb * 128, c0 = cb * 128;
  const int t_ = threadIdx.x, w = t_ >> 6, l = t_ & 63, lo4 = l & 15, g = l >> 4;
  const int mh = w >> 1, ch = w & 1;
  const int srow = w * 16 + (l >> 2), sch = l & 3;
  const int spos = sch ^ ((l >> 3) & 3);
  const int rpos = g ^ ((lo4 >> 1) & 3);
  const bf16* gA0 = &XTx[((size_t)(b * kN + n0 + srow)) * kC + sch * 8];
  const bf16* gA1 = gA0 + (size_t)64 * kC;
  const bf16* gB0 = &Wv[(size_t)(c0 + srow) * kC + sch * 8];
  const bf16* gB1 = gB0 + (size_t)64 * kC;
  f32x4 acc[4][4] = {};
  bf16x8 ra0, ra1, rb0, rb1;
  ra0 = *(const bf16x8*)&gA0[0];
  ra1 = *(const bf16x8*)&gA1[0];
  rb0 = *(const bf16x8*)&gB0[0];
  rb1 = *(const bf16x8*)&gB1[0];
  *(bf16x8*)&As[0][srow][spos * 8] = ra0;
  *(bf16x8*)&As[0][srow + 64][spos * 8] = ra1;
  *(bf16x8*)&Bs[0][srow][spos * 8] = rb0;
  *(bf16x8*)&Bs[0][srow + 64][spos * 8] = rb1;
  __syncthreads();
  for (int tt = 0; tt < 16; tt++) {
    const int buf = tt & 1;
    if (tt < 15) {
      const int k0 = (tt + 1) * 32;
      ra0 = *(const bf16x8*)&gA0[k0];
      ra1 = *(const bf16x8*)&gA1[k0];
      rb0 = *(const bf16x8*)&gB0[k0];
      rb1 = *(const bf16x8*)&gB1[k0];
    }
    bf16x8 af[4], bfr[4];
#pragma unroll
    for (int nf = 0; nf < 4; nf++)
      af[nf] = *(const bf16x8*)&As[buf][mh * 64 + nf * 16 + lo4][rpos * 8];
#pragma unroll
    for (int cf = 0; cf < 4; cf++)
      bfr[cf] = *(const bf16x8*)&Bs[buf][ch * 64 + cf * 16 + lo4][rpos * 8];
#pragma unroll
    for (int nf = 0; nf < 4; nf++)
#pragma unroll
      for (int cf = 0; cf < 4; cf++)
        acc[nf][cf] = MFMA16(af[nf], bfr[cf], acc[nf][cf]);
    if (tt < 15) {
      *(bf16x8*)&As[buf ^ 1][srow][spos * 8] = ra0;
      *(bf16x8*)&As[buf ^ 1][srow + 64][spos * 8] = ra1;
      *(bf16x8*)&Bs[buf ^ 1][srow][spos * 8] = rb0;
      *(bf16x8*)&Bs[buf ^ 1][srow + 64][spos * 8] = rb1;
    }
    __syncthreads();
  }
#pragma unroll
  for (int cf = 0; cf < 4; cf++) {
    const int c = c0 + ch * 64 + cf * 16 + lo4;
    const float bvv = bv[c];
#pragma unroll
    for (int nf = 0; nf < 4; nf++) {
      const int nbase = n0 + mh * 64 + nf * 16 + g * 4;
      bf16x4 o;
#pragma unroll
      for (int r = 0; r < 4; r++) o[r] = (bf16)(acc[nf][cf][r] + bvv);
      *(bf16x4*)&xv2[(((size_t)b * 32 + (nbase >> 6)) * kC + c) * 64 +
                     (nbase & 63)] = o;
    }
  }
}

// ---------------- pass 1: U^T[m][n] exp-factors; COALESCED stores via LDS
// transpose (XOR-swizzled 8B units); partial S[n] via atomics.
__global__ __launch_bounds__(256) void k_sum(
    const bf16* __restrict__ qT, const bf16* __restrict__ kT,
    const int* __restrict__ mask, const float* __restrict__ cnt,
    bf16* __restrict__ UT, float* __restrict__ Ssum) {
  __shared__ __align__(16) bf16 kts[2][64][128];
  __shared__ __align__(16) bf16 Ubuf[64][64];
  __shared__ int mss[2][64];
  const int blk = blockIdx.x;
  const int b = blk & 7, nb = (blk >> 3) & 31, mh2 = blk >> 8;
  const int m00 = mh2 * 1024;
  const int t_ = threadIdx.x, w = t_ >> 6, l = t_ & 63, lo4 = l & 15, g = l >> 4;
  const float invd = 1.0f / (cnt[b] + 1e-9f);
  const int n0 = nb * 64;
  bf16x8 aq[4];
#pragma unroll
  for (int ks = 0; ks < 4; ks++)
    aq[ks] = *(const bf16x8*)&qT[((size_t)(b * kN + n0 + w * 16 + lo4)) * kC4 +
                                 ks * 32 + g * 8];
  const int nq = n0 + w * 16 + g * 4;
  const int4 mi = *(const int4*)&mask[b * kN + nq];
  const int mn4[4] = {mi.x, mi.y, mi.z, mi.w};
  float rs4[4] = {0.0f, 0.0f, 0.0f, 0.0f};
  bf16x8 rg[4];
#pragma unroll
  for (int i = 0; i < 4; i++) {
    const int row = w * 16 + i * 4 + g;
    const int q = (l & 15) ^ (row & 7);
    rg[i] = *(const bf16x8*)&kT[((size_t)(b * kN + m00 + row)) * kC4 + q * 8];
  }
#pragma unroll
  for (int i = 0; i < 4; i++) {
    const int row = w * 16 + i * 4 + g;
    *(bf16x8*)&kts[0][row][(l & 15) * 8] = rg[i];
  }
  if (t_ < 16)
    *(int4*)&mss[0][t_ * 4] = *(const int4*)&mask[b * kN + m00 + t_ * 4];
  __syncthreads();
  for (int tt = 0; tt < 16; tt++) {
    const int buf = tt & 1;
    if (tt < 15) {
      const int m0 = m00 + (tt + 1) * 64;
#pragma unroll
      for (int i = 0; i < 4; i++) {
        const int row = w * 16 + i * 4 + g;
        const int q = (l & 15) ^ (row & 7);
        rg[i] = *(const bf16x8*)&kT[((size_t)(b * kN + m0 + row)) * kC4 + q * 8];
      }
    }
#pragma unroll
    for (int mf = 0; mf < 4; mf++) {
      f32x4 e = {};
#pragma unroll
      for (int ks = 0; ks < 4; ks++) {
        const bf16x8 bk =
            *(const bf16x8*)&kts[buf][mf * 16 + lo4]
                                 [((ks * 4 + g) ^ (lo4 & 7)) * 8];
        e = MFMA16(aq[ks], bk, e);
      }
      const int mmv = mss[buf][mf * 16 + lo4];
      bf16x4 pk;
#pragma unroll
      for (int r = 0; r < 4; r++) {
        const float u = mmv ? (mn4[r] ? __expf(e[r] * invd) : 1.0f) : 0.0f;
        pk[r] = (bf16)u;
        rs4[r] += (float)pk[r];
      }
      *(bf16x4*)&Ubuf[mf * 16 + lo4][((w * 4 + g) ^ lo4) * 4] = pk;
    }
    __syncthreads();
    if (tt < 15) {
#pragma unroll
      for (int i = 0; i < 4; i++) {
        const int row = w * 16 + i * 4 + g;
        *(bf16x8*)&kts[buf ^ 1][row][(l & 15) * 8] = rg[i];
      }
      if (t_ < 16)
        *(int4*)&mss[buf ^ 1][t_ * 4] =
            *(const int4*)&mask[b * kN + m00 + (tt + 1) * 64 + t_ * 4];
    }
    {
      const int row = t_ >> 2, q = t_ & 3;
      bf16x4 seg[4];
#pragma unroll
      for (int k = 0; k < 4; k++) {
        const int us = q * 4 + k;
        seg[k] = *(const bf16x4*)&Ubuf[row][(us ^ (row & 15)) * 4];
      }
      bf16x8 s0, s1;
#pragma unroll
      for (int j = 0; j < 4; j++) {
        s0[j] = seg[0][j];
        s0[4 + j] = seg[1][j];
        s1[j] = seg[2][j];
        s1[4 + j] = seg[3][j];
      }
      bf16* orow =
          &UT[((size_t)(b * kN + m00 + tt * 64 + row)) * kN + n0 + q * 16];
      *(bf16x8*)&orow[0] = s0;
      *(bf16x8*)&orow[8] = s1;
    }
    __syncthreads();
  }
#pragma unroll
  for (int r = 0; r < 4; r++) {
#pragma unroll
    for (int off = 1; off < 16; off <<= 1) rs4[r] += __shfl_xor(rs4[r], off);
  }
  if (lo4 == 0) {
#pragma unroll
    for (int r = 0; r < 4; r++) atomicAdd(&Ssum[b * kN + nq + r], rs4[r]);
  }
}

// ---------------- Ssum -> 1/Ssum in place
__global__ __launch_bounds__(256) void k_invs(float* __restrict__ Ssum) {
  const int i = blockIdx.x * 256 + threadIdx.x;
  Ssum[i] = 1.0f / Ssum[i];
}

// -------- pass 2: x_r^T[m][c] = sum_n UT[m][n]*(xv2[c][n]*invS[n]); h=x-x_r
// 128m x 128c, 4 waves, depth-2 reg pipeline (r13 config) + fused invS on B.
__global__ __launch_bounds__(256, 2) void k_attn2(
    const bf16* __restrict__ UT, const bf16* __restrict__ xv2,
    const float* __restrict__ invS, const float* __restrict__ x,
    bf16* __restrict__ hT) {
  __shared__ __align__(16) bf16 As[2][128][32];
  __shared__ __align__(16) bf16 Bs[2][128][32];
  const int blk = blockIdx.x;  // 512 = 8b x (16mb x 4cb)
  const int b = blk & 7, tile = blk >> 3;
  const int cb = tile & 3, mb = tile >> 2;
  const int m0 = mb * 128, c0 = cb * 128;
  const int t_ = threadIdx.x, w = t_ >> 6, l = t_ & 63, lo4 = l & 15, g = l >> 4;
  const int mh = w >> 1, ch = w & 1;
  const int srow = w * 16 + (l >> 2), sch = l & 3;
  const int spos = sch ^ ((l >> 3) & 3);
  const int rpos = g ^ ((lo4 >> 1) & 3);
  const bf16* gA0 = &UT[((size_t)(b * kN + m0 + srow)) * kN + sch * 8];
  const bf16* gA1 = gA0 + (size_t)64 * kN;
  const bf16* gB0 = &xv2[(((size_t)b * 32) * kC + c0 + srow) * 64 + sch * 8];
  const bf16* gB1 = gB0 + (size_t)64 * 64;
  const float* isB = &invS[b * kN];
  f32x4 acc[4][4] = {};
#define SCALE8(v, s0, s1, o)                                                   \
  _Pragma("unroll") for (int j = 0; j < 4; j++) {                              \
    o[j] = (bf16)((float)v[j] * s0[j]);                                        \
    o[4 + j] = (bf16)((float)v[4 + j] * s1[j]);                                \
  }
  // prologue: iter0 -> LDS[0]; iter1 pending in regs
  {
    const bf16x8 a0 = *(const bf16x8*)&gA0[0];
    const bf16x8 a1 = *(const bf16x8*)&gA1[0];
    const bf16x8 b0 = *(const bf16x8*)&gB0[0];
    const bf16x8 b1 = *(const bf16x8*)&gB1[0];
    const f32x4 s0 = *(const f32x4*)&isB[sch * 8];
    const f32x4 s1 = *(const f32x4*)&isB[sch * 8 + 4];
    bf16x8 o0, o1;
    SCALE8(b0, s0, s1, o0);
    SCALE8(b1, s0, s1, o1);
    *(bf16x8*)&As[0][srow][spos * 8] = a0;
    *(bf16x8*)&As[0][srow + 64][spos * 8] = a1;
    *(bf16x8*)&Bs[0][srow][spos * 8] = o0;
    *(bf16x8*)&Bs[0][srow + 64][spos * 8] = o1;
  }
  bf16x8 oA0, oA1, oB0, oB1, eA0, eA1, eB0, eB1;
  f32x4 oS0, oS1, eS0, eS1;
  oA0 = *(const bf16x8*)&gA0[32];
  oA1 = *(const bf16x8*)&gA1[32];
  oB0 = *(const bf16x8*)&gB0[32];
  oB1 = *(const bf16x8*)&gB1[32];
  oS0 = *(const f32x4*)&isB[32 + sch * 8];
  oS1 = *(const f32x4*)&isB[32 + sch * 8 + 4];
  __syncthreads();
#define FRAGS_MFMA(BUF)                                                        \
  {                                                                            \
    bf16x8 af[4], bfr[4];                                                      \
    _Pragma("unroll") for (int mf = 0; mf < 4; mf++) af[mf] =                  \
        *(const bf16x8*)&As[BUF][mh * 64 + mf * 16 + lo4][rpos * 8];           \
    _Pragma("unroll") for (int cf = 0; cf < 4; cf++) bfr[cf] =                 \
        *(const bf16x8*)&Bs[BUF][ch * 64 + cf * 16 + lo4][rpos * 8];           \
    _Pragma("unroll") for (int mf = 0; mf < 4; mf++)                           \
        _Pragma("unroll") for (int cf = 0; cf < 4; cf++) acc[mf][cf] =         \
            MFMA16(af[mf], bfr[cf], acc[mf][cf]);                              \
  }
  for (int tt2 = 0; tt2 < 64; tt2 += 2) {
    // ---- even iter tt2 (buf 0): issue loads for tt2+2
    if (tt2 + 2 < 64) {
      const int n2 = tt2 + 2;
      eA0 = *(const bf16x8*)&gA0[n2 * 32];
      eA1 = *(const bf16x8*)&gA1[n2 * 32];
      const size_t bo = (size_t)(n2 >> 1) * (kC * 64) + (n2 & 1) * 32;
      eB0 = *(const bf16x8*)&gB0[bo];
      eB1 = *(const bf16x8*)&gB1[bo];
      eS0 = *(const f32x4*)&isB[n2 * 32 + sch * 8];
      eS1 = *(const f32x4*)&isB[n2 * 32 + sch * 8 + 4];
    }
    FRAGS_MFMA(0);
    {
      bf16x8 o0, o1;
      SCALE8(oB0, oS0, oS1, o0);
      SCALE8(oB1, oS0, oS1, o1);
      *(bf16x8*)&As[1][srow][spos * 8] = oA0;
      *(bf16x8*)&As[1][srow + 64][spos * 8] = oA1;
      *(bf16x8*)&Bs[1][srow][spos * 8] = o0;
      *(bf16x8*)&Bs[1][srow + 64][spos * 8] = o1;
    }
    __syncthreads();
    // ---- odd iter tt2+1 (buf 1): issue loads for tt2+3
    if (tt2 + 3 < 64) {
      const int n3 = tt2 + 3;
      oA0 = *(const bf16x8*)&gA0[n3 * 32];
      oA1 = *(const bf16x8*)&gA1[n3 * 32];
      const size_t bo = (size_t)(n3 >> 1) * (kC * 64) + (n3 & 1) * 32;
      oB0 = *(const bf16x8*)&gB0[bo];
      oB1 = *(const bf16x8*)&gB1[bo];
      oS0 = *(const f32x4*)&isB[n3 * 32 + sch * 8];
      oS1 = *(const f32x4*)&isB[n3 * 32 + sch * 8 + 4];
    }
    FRAGS_MFMA(1);
    if (tt2 + 2 < 64) {
      bf16x8 o0, o1;
      SCALE8(eB0, eS0, eS1, o0);
      SCALE8(eB1, eS0, eS1, o1);
      *(bf16x8*)&As[0][srow][spos * 8] = eA0;
      *(bf16x8*)&As[0][srow + 64][spos * 8] = eA1;
      *(bf16x8*)&Bs[0][srow][spos * 8] = o0;
      *(bf16x8*)&Bs[0][srow + 64][spos * 8] = o1;
    }
    __syncthreads();
  }
#undef FRAGS_MFMA
#undef SCALE8
  // epilogue: h = x - x_r; per-wave LDS transpose (alias As) -> hT[m][c]
  bf16* bncw = ((bf16*)As) + w * 16 * 72;
#pragma unroll
  for (int mf = 0; mf < 4; mf++) {
    const int mbase = m0 + mh * 64 + mf * 16;
    float hh[4][4];
#pragma unroll
    for (int cf = 0; cf < 4; cf++) {
      const int c = c0 + ch * 64 + cf * 16 + lo4;
      const f32x4 xval =
          *(const f32x4*)&x[((size_t)(b * kC + c)) * kN + mbase + g * 4];
#pragma unroll
      for (int r = 0; r < 4; r++) hh[cf][r] = xval[r] - acc[mf][cf][r];
    }
#pragma unroll
    for (int cf = 0; cf < 4; cf++)
#pragma unroll
      for (int r = 0; r < 4; r++)
        bncw[(4 * g + r) * 72 + cf * 16 + lo4] = (bf16)hh[cf][r];
    {
      const int rr = l >> 2, seg = (l & 3) * 16;
      const bf16x8 v0 = *(const bf16x8*)&bncw[rr * 72 + seg];
      const bf16x8 v1 = *(const bf16x8*)&bncw[rr * 72 + seg + 8];
      bf16* orow =
          &hT[((size_t)(b * kN + mbase + rr)) * kC + c0 + ch * 64 + seg];
      *(bf16x8*)&orow[0] = v0;
      *(bf16x8*)&orow[8] = v1;
    }
  }
}

// -------- final: D[n][c] = hT[n][k] wt[c][k]; BN+ReLU+residual
__global__ __launch_bounds__(256, 2) void k_final(
    const bf16* __restrict__ hT, const bf16* __restrict__ wt_bf,
    const float* __restrict__ x, const float* __restrict__ bt,
    const float* __restrict__ beta, const float* __restrict__ rmean,
    const float* __restrict__ invg, float* __restrict__ out) {
  __shared__ __align__(16) bf16 As[2][128][32];
  __shared__ __align__(16) bf16 Bs[2][128][32];
  const int blk = blockIdx.x;  // 512 = 8b x (16nb x 4cb)
  const int b = blk & 7, tile = blk >> 3;
  const int cb = tile & 3, nb = tile >> 2;
  const int n0 = nb * 128, c0 = cb * 128;
  const int t_ = threadIdx.x, w = t_ >> 6, l = t_ & 63, lo4 = l & 15, g = l >> 4;
  const int mh = w >> 1, ch = w & 1;
  const int srow = w * 16 + (l >> 2), sch = l & 3;
  const int spos = sch ^ ((l >> 3) & 3);
  const int rpos = g ^ ((lo4 >> 1) & 3);
  const bf16* gA0 = &hT[((size_t)(b * kN + n0 + srow)) * kC + sch * 8];
  const bf16* gA1 = gA0 + (size_t)64 * kC;
  const bf16* gB0 = &wt_bf[(size_t)(c0 + srow) * kC + sch * 8];
  const bf16* gB1 = gB0 + (size_t)64 * kC;
  f32x4 acc[4][4] = {};
  bf16x8 ra0, ra1, rb0, rb1;
  ra0 = *(const bf16x8*)&gA0[0];
  ra1 = *(const bf16x8*)&gA1[0];
  rb0 = *(const bf16x8*)&gB0[0];
  rb1 = *(const bf16x8*)&gB1[0];
  *(bf16x8*)&As[0][srow][spos * 8] = ra0;
  *(bf16x8*)&As[0][srow + 64][spos * 8] = ra1;
  *(bf16x8*)&Bs[0][srow][spos * 8] = rb0;
  *(bf16x8*)&Bs[0][srow + 64][spos * 8] = rb1;
  __syncthreads();
  for (int tt = 0; tt < 16; tt++) {
    const int buf = tt & 1;
    if (tt < 15) {
      const int k0 = (tt + 1) * 32;
      ra0 = *(const bf16x8*)&gA0[k0];
      ra1 = *(const bf16x8*)&gA1[k0];
      rb0 = *(const bf16x8*)&gB0[k0];
      rb1 = *(const bf16x8*)&gB1[k0];
    }
    bf16x8 af[4], bfr[4];
#pragma unroll
    for (int nf = 0; nf < 4; nf++)
      af[nf] = *(const bf16x8*)&As[buf][mh * 64 + nf * 16 + lo4][rpos * 8];
#pragma unroll
    for (int cf = 0; cf < 4; cf++)
      bfr[cf] = *(const bf16x8*)&Bs[buf][ch * 64 + cf * 16 + lo4][rpos * 8];
#pragma unroll
    for (int nf = 0; nf < 4; nf++)
#pragma unroll
      for (int cf = 0; cf < 4; cf++)
        acc[nf][cf] = MFMA16(af[nf], bfr[cf], acc[nf][cf]);
    if (tt < 15) {
      *(bf16x8*)&As[buf ^ 1][srow][spos * 8] = ra0;
      *(bf16x8*)&As[buf ^ 1][srow + 64][spos * 8] = ra1;
      *(bf16x8*)&Bs[buf ^ 1][srow][spos * 8] = rb0;
      *(bf16x8*)&Bs[buf ^ 1][srow + 64][spos * 8] = rb1;
    }
    __syncthreads();
  }
#pragma unroll
  for (int cf = 0; cf < 4; cf++) {
    const int c = c0 + ch * 64 + cf * 16 + lo4;
    const float btv = bt[c], rmv = rmean[c], igv = invg[c], bev = beta[c];
#pragma unroll
    for (int nf = 0; nf < 4; nf++) {
      const int nbase = n0 + mh * 64 + nf * 16 + g * 4;
      const size_t base = ((size_t)(b * kC + c)) * kN + nbase;
      const f32x4 xval = *(const f32x4*)&x[base];
      f32x4 o;
#pragma unroll
      for (int r = 0; r < 4; r++) {
        float v = (acc[nf][cf][r] + btv - rmv) * igv + bev;
        v = fmaxf(v, 0.0f);
        o[r] = xval[r] + v;
      }
      *(f32x4*)&out[base] = o;
    }
  }
}

extern "C" void kernel_launch(void* const* d_in, const int* in_sizes, int n_in,
                              void* d_out, int out_size, void* d_ws,
                              size_t ws_size, hipStream_t stream) {
  const float* x = (const float*)d_in[0];
  const float* query = (const float*)d_in[1];
  const int* mask = (const int*)d_in[2];
  const float* wqk = (const float*)d_in[3];
  const float* wv = (const float*)d_in[4];
  const float* bv = (const float*)d_in[5];
  const float* wt = (const float*)d_in[6];
  const float* bt = (const float*)d_in[7];
  const float* gamma = (const float*)d_in[8];
  const float* beta = (const float*)d_in[9];
  const float* rmean = (const float*)d_in[10];
  const float* rvar = (const float*)d_in[11];
  float* out = (float*)d_out;
  char* wsb = (char*)d_ws;

  const size_t MB = 1024 * 1024;
  bf16* UT = (bf16*)wsb;                        // 64 MB [b][m][n]
  bf16* trbufQ = (bf16*)wsb;                    // 16 MB (in UT dead zone)
  bf16* trbufX = (bf16*)(wsb + 16 * MB);        // 16 MB (in UT dead zone)
  bf16* xv2 = (bf16*)(wsb + 64 * MB);           // 16 MB tiled
  bf16* hT = (bf16*)(wsb + 80 * MB);            // 8 MB [b][n][c]
  bf16* qT = (bf16*)(wsb + 88 * MB);            // 4 MB
  bf16* kT = (bf16*)(wsb + 92 * MB);            // 4 MB
  bf16* wqk_bf = (bf16*)(wsb + 96 * MB);        // 128 KB
  bf16* wv_bf = wqk_bf + 65536;                 // 512 KB
  bf16* wt_bf = wv_bf + 262144;                 // 512 KB
  float* invg = (float*)(wt_bf + 262144);       // 2 KB
  float* Ssum = invg + 512;                     // 64 KB (becomes invS)
  float* cnt = Ssum + kB * kN;                  // 32 B

  k_prep<<<136, 256, 0, stream>>>(mask, wqk, wv, wt, gamma, rvar, cnt, wqk_bf,
                                  wv_bf, wt_bf, invg, Ssum);
  k_tr2<<<dim3(kN / 64, kC / 32, 16), 256, 0, stream>>>(query, x, trbufQ,
                                                        trbufX);
  k_projQK<<<dim3(16, kB, 2), 256, 0, stream>>>(trbufQ, trbufX, wqk_bf, qT,
                                                kT);
  k_projV<<<512, 256, 0, stream>>>(trbufX, wv_bf, bv, xv2);
  k_sum<<<512, 256, 0, stream>>>(qT, kT, mask, cnt, UT, Ssum);
  k_invs<<<64, 256, 0, stream>>>(Ssum);
  k_attn2<<<512, 256, 0, stream>>>(UT, xv2, Ssum, x, hT);
  k_final<<<512, 256, 0, stream>>>(hT, wt_bf, x, bt, beta, rmean, invg, out);
}

// Round 16
// 153.949 us; speedup vs baseline: 1.1688x; 1.0628x over previous
//
#include <hip/hip_runtime.h>
#include <math.h>

typedef __bf16 bf16;
typedef bf16 bf16x8 __attribute__((ext_vector_type(8)));
typedef bf16 bf16x4 __attribute__((ext_vector_type(4)));
typedef float f32x4 __attribute__((ext_vector_type(4)));

constexpr int kB = 8, kC = 512, kC4 = 128, kN = 2048;

#define MFMA16(a, b, c) __builtin_amdgcn_mfma_f32_16x16x32_bf16(a, b, c, 0, 0, 0)
#define MFMA8(a, b, c) \
  __builtin_amdgcn_mfma_f32_16x16x32_fp8_fp8(a, b, c, 0, 0, 0)

__device__ __forceinline__ unsigned pack4_fp8(float a, float b, float c,
                                              float d) {
  unsigned v = 0;
  v = __builtin_amdgcn_cvt_pk_fp8_f32(a, b, v, false);
  v = __builtin_amdgcn_cvt_pk_fp8_f32(c, d, v, true);
  return v;
}

// ---------------------------------------------------------------- prep
__global__ __launch_bounds__(256) void k_prep(
    const int* __restrict__ mask, const float* __restrict__ wqk,
    const float* __restrict__ wv, const float* __restrict__ wt,
    const float* __restrict__ gamma, const float* __restrict__ rvar,
    float* __restrict__ cnt, bf16* __restrict__ wqk_bf,
    bf16* __restrict__ wv_bf, bf16* __restrict__ wt_bf,
    float* __restrict__ invg, float* __restrict__ Ssum) {
  const int t = threadIdx.x;
  if (blockIdx.x < 8) {
    const int b = blockIdx.x;
    int s = 0;
    for (int i = t; i < kN; i += 256) s += mask[b * kN + i];
    __shared__ int red[256];
    red[t] = s;
    __syncthreads();
    for (int off = 128; off > 0; off >>= 1) {
      if (t < off) red[t] += red[t + off];
      __syncthreads();
    }
    if (t == 0) cnt[b] = (float)red[0];
    return;
  }
  const int total = 65536 + 262144 + 262144 + 512 + 16384;
  for (int i = (blockIdx.x - 8) * 256 + t; i < total; i += 128 * 256) {
    if (i < 65536) {
      wqk_bf[i] = (bf16)wqk[i];
    } else if (i < 327680) {
      wv_bf[i - 65536] = (bf16)wv[i - 65536];
    } else if (i < 589824) {
      wt_bf[i - 327680] = (bf16)wt[i - 327680];
    } else if (i < 590336) {
      const int j = i - 589824;
      invg[j] = gamma[j] * rsqrtf(rvar[j] + 1e-5f);
    } else {
      Ssum[i - 590336] = 0.0f;
    }
  }
}

// ---------------- transpose+convert both inputs: [C][N] f32 -> [N][C] bf16
__global__ __launch_bounds__(256) void k_tr2(const float* __restrict__ Q,
                                             const float* __restrict__ X,
                                             bf16* __restrict__ XTq,
                                             bf16* __restrict__ XTx) {
  __shared__ float tile[32][69];
  const int z = blockIdx.z, b = z & 7;
  const float* Xs = (z < 8) ? Q : X;
  bf16* XT = (z < 8) ? XTq : XTx;
  const int c0 = blockIdx.y * 32, n0 = blockIdx.x * 64;
  const int t = threadIdx.x;
  const int cc = t >> 4, n4 = (t & 15) * 4;
#pragma unroll
  for (int p = 0; p < 2; p++) {
    const int c = p * 16 + cc;
    const f32x4 v =
        *(const f32x4*)&Xs[((size_t)(b * kC + c0 + c)) * kN + n0 + n4];
    tile[c][n4 + 0] = v[0];
    tile[c][n4 + 1] = v[1];
    tile[c][n4 + 2] = v[2];
    tile[c][n4 + 3] = v[3];
  }
  __syncthreads();
  const int n = t >> 2, c8 = (t & 3) * 8;
  bf16x8 o;
#pragma unroll
  for (int j = 0; j < 8; j++) o[j] = (bf16)tile[c8 + j][n];
  *(bf16x8*)&XT[((size_t)(b * kN + n0 + n)) * kC + c0 + c8] = o;
}

// -------- q/k projections (staged GEMM): OT[b][n][128] = (wqk @ src)^T
__global__ __launch_bounds__(256, 2) void k_projQK(
    const bf16* __restrict__ XTq, const bf16* __restrict__ XTx,
    const bf16* __restrict__ W, bf16* __restrict__ qT, bf16* __restrict__ kT) {
  __shared__ __align__(16) bf16 As[2][128][32];
  __shared__ __align__(16) bf16 Bs[2][128][32];
  const int nb = blockIdx.x, b = blockIdx.y, src = blockIdx.z;
  const bf16* XT = src ? XTx : XTq;
  bf16* OT = src ? kT : qT;
  const int n0 = nb * 128;
  const int t_ = threadIdx.x, w = t_ >> 6, l = t_ & 63, lo4 = l & 15, g = l >> 4;
  const int mh = w >> 1, ch = w & 1;
  const int srow = w * 16 + (l >> 2), sch = l & 3;
  const int spos = sch ^ ((l >> 3) & 3);
  const int rpos = g ^ ((lo4 >> 1) & 3);
  const bf16* gA0 = &XT[((size_t)(b * kN + n0 + srow)) * kC + sch * 8];
  const bf16* gA1 = gA0 + (size_t)64 * kC;
  const bf16* gB0 = &W[(size_t)srow * kC + sch * 8];
  const bf16* gB1 = gB0 + (size_t)64 * kC;
  f32x4 acc[4][4] = {};
  bf16x8 ra0, ra1, rb0, rb1;
  ra0 = *(const bf16x8*)&gA0[0];
  ra1 = *(const bf16x8*)&gA1[0];
  rb0 = *(const bf16x8*)&gB0[0];
  rb1 = *(const bf16x8*)&gB1[0];
  *(bf16x8*)&As[0][srow][spos * 8] = ra0;
  *(bf16x8*)&As[0][srow + 64][spos * 8] = ra1;
  *(bf16x8*)&Bs[0][srow][spos * 8] = rb0;
  *(bf16x8*)&Bs[0][srow + 64][spos * 8] = rb1;
  __syncthreads();
  for (int tt = 0; tt < 16; tt++) {
    const int buf = tt & 1;
    if (tt < 15) {
      const int k0 = (tt + 1) * 32;
      ra0 = *(const bf16x8*)&gA0[k0];
      ra1 = *(const bf16x8*)&gA1[k0];
      rb0 = *(const bf16x8*)&gB0[k0];
      rb1 = *(const bf16x8*)&gB1[k0];
    }
    bf16x8 af[4], bfr[4];
#pragma unroll
    for (int nf = 0; nf < 4; nf++)
      af[nf] = *(const bf16x8*)&As[buf][mh * 64 + nf * 16 + lo4][rpos * 8];
#pragma unroll
    for (int cf = 0; cf < 4; cf++)
      bfr[cf] = *(const bf16x8*)&Bs[buf][ch * 64 + cf * 16 + lo4][rpos * 8];
#pragma unroll
    for (int nf = 0; nf < 4; nf++)
#pragma unroll
      for (int cf = 0; cf < 4; cf++)
        acc[nf][cf] = MFMA16(af[nf], bfr[cf], acc[nf][cf]);
    if (tt < 15) {
      *(bf16x8*)&As[buf ^ 1][srow][spos * 8] = ra0;
      *(bf16x8*)&As[buf ^ 1][srow + 64][spos * 8] = ra1;
      *(bf16x8*)&Bs[buf ^ 1][srow][spos * 8] = rb0;
      *(bf16x8*)&Bs[buf ^ 1][srow + 64][spos * 8] = rb1;
    }
    __syncthreads();
  }
  bf16* bncw = ((bf16*)As) + w * 16 * 72;
#pragma unroll
  for (int nf = 0; nf < 4; nf++) {
    const int nbase = n0 + mh * 64 + nf * 16;
#pragma unroll
    for (int cf = 0; cf < 4; cf++)
#pragma unroll
      for (int r = 0; r < 4; r++)
        bncw[(4 * g + r) * 72 + cf * 16 + lo4] = (bf16)acc[nf][cf][r];
    const int rr = l >> 2, seg = (l & 3) * 16;
    const bf16x8 v0 = *(const bf16x8*)&bncw[rr * 72 + seg];
    const bf16x8 v1 = *(const bf16x8*)&bncw[rr * 72 + seg + 8];
    bf16* orow = &OT[((size_t)(b * kN + nbase + rr)) * kC4 + ch * 64 + seg];
    *(bf16x8*)&orow[0] = v0;
    *(bf16x8*)&orow[8] = v1;
  }
}

// -------- value projection (staged GEMM) -> TILED xv2[b][n>>6][c][n&63]
__global__ __launch_bounds__(256, 2) void k_projV(
    const bf16* __restrict__ XTx, const bf16* __restrict__ Wv,
    const float* __restrict__ bv, bf16* __restrict__ xv2) {
  __shared__ __align__(16) bf16 As[2][128][32];
  __shared__ __align__(16) bf16 Bs[2][128][32];
  const int blk = blockIdx.x;  // 512 = 8b x (16nb x 4cb)
  const int b = blk & 7, tile = blk >> 3;
  const int cb = tile & 3, nb = tile >> 2;
  const int n0 = nb * 128, c0 = cb * 128;
  const int t_ = threadIdx.x, w = t_ >> 6, l = t_ & 63, lo4 = l & 15, g = l >> 4;
  const int mh = w >> 1, ch = w & 1;
  const int srow = w * 16 + (l >> 2), sch = l & 3;
  const int spos = sch ^ ((l >> 3) & 3);
  const int rpos = g ^ ((lo4 >> 1) & 3);
  const bf16* gA0 = &XTx[((size_t)(b * kN + n0 + srow)) * kC + sch * 8];
  const bf16* gA1 = gA0 + (size_t)64 * kC;
  const bf16* gB0 = &Wv[(size_t)(c0 + srow) * kC + sch * 8];
  const bf16* gB1 = gB0 + (size_t)64 * kC;
  f32x4 acc[4][4] = {};
  bf16x8 ra0, ra1, rb0, rb1;
  ra0 = *(const bf16x8*)&gA0[0];
  ra1 = *(const bf16x8*)&gA1[0];
  rb0 = *(const bf16x8*)&gB0[0];
  rb1 = *(const bf16x8*)&gB1[0];
  *(bf16x8*)&As[0][srow][spos * 8] = ra0;
  *(bf16x8*)&As[0][srow + 64][spos * 8] = ra1;
  *(bf16x8*)&Bs[0][srow][spos * 8] = rb0;
  *(bf16x8*)&Bs[0][srow + 64][spos * 8] = rb1;
  __syncthreads();
  for (int tt = 0; tt < 16; tt++) {
    const int buf = tt & 1;
    if (tt < 15) {
      const int k0 = (tt + 1) * 32;
      ra0 = *(const bf16x8*)&gA0[k0];
      ra1 = *(const bf16x8*)&gA1[k0];
      rb0 = *(const bf16x8*)&gB0[k0];
      rb1 = *(const bf16x8*)&gB1[k0];
    }
    bf16x8 af[4], bfr[4];
#pragma unroll
    for (int nf = 0; nf < 4; nf++)
      af[nf] = *(const bf16x8*)&As[buf][mh * 64 + nf * 16 + lo4][rpos * 8];
#pragma unroll
    for (int cf = 0; cf < 4; cf++)
      bfr[cf] = *(const bf16x8*)&Bs[buf][ch * 64 + cf * 16 + lo4][rpos * 8];
#pragma unroll
    for (int nf = 0; nf < 4; nf++)
#pragma unroll
      for (int cf = 0; cf < 4; cf++)
        acc[nf][cf] = MFMA16(af[nf], bfr[cf], acc[nf][cf]);
    if (tt < 15) {
      *(bf16x8*)&As[buf ^ 1][srow][spos * 8] = ra0;
      *(bf16x8*)&As[buf ^ 1][srow + 64][spos * 8] = ra1;
      *(bf16x8*)&Bs[buf ^ 1][srow][spos * 8] = rb0;
      *(bf16x8*)&Bs[buf ^ 1][srow + 64][spos * 8] = rb1;
    }
    __syncthreads();
  }
#pragma unroll
  for (int cf = 0; cf < 4; cf++) {
    const int c = c0 + ch * 64 + cf * 16 + lo4;
    const float bvv = bv[c];
#pragma unroll
    for (int nf = 0; nf < 4; nf++) {
      const int nbase = n0 + mh * 64 + nf * 16 + g * 4;
      bf16x4 o;
#pragma unroll
      for (int r = 0; r < 4; r++) o[r] = (bf16)(acc[nf][cf][r] + bvv);
      *(bf16x4*)&xv2[(((size_t)b * 32 + (nbase >> 6)) * kC + c) * 64 +
                     (nbase & 63)] = o;
    }
  }
}

// ---------------- pass 1: U^T[m][n] exp-factors -> fp8 UT8; partial S[n].
__global__ __launch_bounds__(256) void k_sum(
    const bf16* __restrict__ qT, const bf16* __restrict__ kT,
    const int* __restrict__ mask, const float* __restrict__ cnt,
    unsigned char* __restrict__ UT8, float* __restrict__ Ssum) {
  __shared__ __align__(16) bf16 kts[2][64][128];
  __shared__ __align__(16) unsigned Ubuf[64][16];
  __shared__ int mss[2][64];
  const int blk = blockIdx.x;
  const int b = blk & 7, nb = (blk >> 3) & 31, mh2 = blk >> 8;
  const int m00 = mh2 * 1024;
  const int t_ = threadIdx.x, w = t_ >> 6, l = t_ & 63, lo4 = l & 15, g = l >> 4;
  const float invd = 1.0f / (cnt[b] + 1e-9f);
  const int n0 = nb * 64;
  bf16x8 aq[4];
#pragma unroll
  for (int ks = 0; ks < 4; ks++)
    aq[ks] = *(const bf16x8*)&qT[((size_t)(b * kN + n0 + w * 16 + lo4)) * kC4 +
                                 ks * 32 + g * 8];
  const int nq = n0 + w * 16 + g * 4;
  const int4 mi = *(const int4*)&mask[b * kN + nq];
  const int mn4[4] = {mi.x, mi.y, mi.z, mi.w};
  float rs4[4] = {0.0f, 0.0f, 0.0f, 0.0f};
  bf16x8 rg[4];
#pragma unroll
  for (int i = 0; i < 4; i++) {
    const int row = w * 16 + i * 4 + g;
    const int q = (l & 15) ^ (row & 7);
    rg[i] = *(const bf16x8*)&kT[((size_t)(b * kN + m00 + row)) * kC4 + q * 8];
  }
#pragma unroll
  for (int i = 0; i < 4; i++) {
    const int row = w * 16 + i * 4 + g;
    *(bf16x8*)&kts[0][row][(l & 15) * 8] = rg[i];
  }
  if (t_ < 16)
    *(int4*)&mss[0][t_ * 4] = *(const int4*)&mask[b * kN + m00 + t_ * 4];
  __syncthreads();
  for (int tt = 0; tt < 16; tt++) {
    const int buf = tt & 1;
    if (tt < 15) {
      const int m0 = m00 + (tt + 1) * 64;
#pragma unroll
      for (int i = 0; i < 4; i++) {
        const int row = w * 16 + i * 4 + g;
        const int q = (l & 15) ^ (row & 7);
        rg[i] = *(const bf16x8*)&kT[((size_t)(b * kN + m0 + row)) * kC4 + q * 8];
      }
    }
#pragma unroll
    for (int mf = 0; mf < 4; mf++) {
      f32x4 e = {};
#pragma unroll
      for (int ks = 0; ks < 4; ks++) {
        const bf16x8 bk =
            *(const bf16x8*)&kts[buf][mf * 16 + lo4]
                                 [((ks * 4 + g) ^ (lo4 & 7)) * 8];
        e = MFMA16(aq[ks], bk, e);
      }
      const int mmv = mss[buf][mf * 16 + lo4];
      float u[4];
#pragma unroll
      for (int r = 0; r < 4; r++) {
        u[r] = mmv ? (mn4[r] ? __expf(e[r] * invd) : 1.0f) : 0.0f;
        rs4[r] += u[r];
      }
      Ubuf[mf * 16 + lo4][(w * 4 + g) ^ lo4] =
          pack4_fp8(u[0], u[1], u[2], u[3]);
    }
    __syncthreads();
    if (tt < 15) {
#pragma unroll
      for (int i = 0; i < 4; i++) {
        const int row = w * 16 + i * 4 + g;
        *(bf16x8*)&kts[buf ^ 1][row][(l & 15) * 8] = rg[i];
      }
      if (t_ < 16)
        *(int4*)&mss[buf ^ 1][t_ * 4] =
            *(const int4*)&mask[b * kN + m00 + (tt + 1) * 64 + t_ * 4];
    }
    {
      const int row = t_ >> 2, q = t_ & 3;
      int4 pkt;
      pkt.x = (int)Ubuf[row][(q * 4 + 0) ^ (row & 15)];
      pkt.y = (int)Ubuf[row][(q * 4 + 1) ^ (row & 15)];
      pkt.z = (int)Ubuf[row][(q * 4 + 2) ^ (row & 15)];
      pkt.w = (int)Ubuf[row][(q * 4 + 3) ^ (row & 15)];
      *(int4*)&UT8[((size_t)(b * kN + m00 + tt * 64 + row)) * kN + n0 +
                   q * 16] = pkt;
    }
    __syncthreads();
  }
#pragma unroll
  for (int r = 0; r < 4; r++) {
#pragma unroll
    for (int off = 1; off < 16; off <<= 1) rs4[r] += __shfl_xor(rs4[r], off);
  }
  if (lo4 == 0) {
#pragma unroll
    for (int r = 0; r < 4; r++) atomicAdd(&Ssum[b * kN + nq + r], rs4[r]);
  }
}

// ---------------- Ssum -> 1/Ssum in place
__global__ __launch_bounds__(256) void k_invs(float* __restrict__ Ssum) {
  const int i = blockIdx.x * 256 + threadIdx.x;
  Ssum[i] = 1.0f / Ssum[i];
}

// ---------------- xv2 (bf16 tiled) * invS[n] -> xv8 (fp8 tiled)
__global__ __launch_bounds__(256) void k_scale(const bf16* __restrict__ xv2,
                                               const float* __restrict__ invS,
                                               unsigned* __restrict__ xv8) {
  const int blk = blockIdx.x;  // 1024 = 8b x 128 parts
  const int b = blk & 7, part = blk >> 3;
  const size_t base = (size_t)b * (32 * kC * 64);
  for (int it = 0; it < 4; it++) {
    const int chunk = part * 1024 + it * 256 + threadIdx.x;
    const size_t e = (size_t)chunk * 8;
    const int n = ((int)(e >> 15)) * 64 + ((int)e & 63);
    const bf16x8 v = *(const bf16x8*)&xv2[base + e];
    const f32x4 s0 = *(const f32x4*)&invS[b * kN + n];
    const f32x4 s1 = *(const f32x4*)&invS[b * kN + n + 4];
    uint2 o;
    o.x = pack4_fp8((float)v[0] * s0[0], (float)v[1] * s0[1],
                    (float)v[2] * s0[2], (float)v[3] * s0[3]);
    o.y = pack4_fp8((float)v[4] * s1[0], (float)v[5] * s1[1],
                    (float)v[6] * s1[2], (float)v[7] * s1[3]);
    *(uint2*)&xv8[(base + e) >> 2] = o;
  }
}

// -------- pass 2 (fp8): x_r^T[m][c] = sum_n UT8[m][n]*xv8[c][n]; h=x-x_r
// 128m x 128c, 4 waves, depth-2 reg pipeline; fp8 tiles (4KB), 16B XOR swz.
__global__ __launch_bounds__(256, 2) void k_attn2(
    const unsigned char* __restrict__ UT8, const unsigned char* __restrict__ xv8,
    const float* __restrict__ x, bf16* __restrict__ hT) {
  __shared__ __align__(16) unsigned char smem[16384];
  unsigned char (*As)[128][32] = (unsigned char (*)[128][32])smem;
  unsigned char (*Bs)[128][32] = (unsigned char (*)[128][32])(smem + 8192);
  const int blk = blockIdx.x;  // 512 = 8b x (16mb x 4cb)
  const int b = blk & 7, tile = blk >> 3;
  const int cb = tile & 3, mb = tile >> 2;
  const int m0 = mb * 128, c0 = cb * 128;
  const int t_ = threadIdx.x, w = t_ >> 6, l = t_ & 63, lo4 = l & 15, g = l >> 4;
  const int mh = w >> 1, ch = w & 1;
  const int srow = t_ >> 1, ps = t_ & 1;
  const int spos = ps ^ ((srow >> 2) & 1);  // 16B-granular swizzle
  const unsigned char* gA = &UT8[((size_t)(b * kN + m0 + srow)) * kN + ps * 16];
  const unsigned char* gB =
      &xv8[(((size_t)b * 32) * kC + c0 + srow) * 64 + ps * 16];
  f32x4 acc[4][4] = {};
  {
    const int4 a = *(const int4*)&gA[0];
    const int4 bb = *(const int4*)&gB[0];
    *(int4*)&As[0][srow][spos * 16] = a;
    *(int4*)&Bs[0][srow][spos * 16] = bb;
  }
  int4 oA, oB, eA, eB;
  oA = *(const int4*)&gA[32];
  oB = *(const int4*)&gB[32];
  __syncthreads();
#define FRAGS_MFMA(BUF)                                                        \
  {                                                                            \
    long af[4], bfr[4];                                                        \
    _Pragma("unroll") for (int mf = 0; mf < 4; mf++) {                         \
      const int row = mh * 64 + mf * 16 + lo4;                                 \
      const int fr = (row >> 2) & 1;                                           \
      af[mf] = *(const long*)&As[BUF][row][((g >> 1) ^ fr) * 16 + (g & 1) * 8];\
    }                                                                          \
    _Pragma("unroll") for (int cf = 0; cf < 4; cf++) {                         \
      const int row = ch * 64 + cf * 16 + lo4;                                 \
      const int fr = (row >> 2) & 1;                                           \
      bfr[cf] =                                                                \
          *(const long*)&Bs[BUF][row][((g >> 1) ^ fr) * 16 + (g & 1) * 8];     \
    }                                                                          \
    _Pragma("unroll") for (int mf = 0; mf < 4; mf++)                           \
        _Pragma("unroll") for (int cf = 0; cf < 4; cf++) acc[mf][cf] =         \
            MFMA8(af[mf], bfr[cf], acc[mf][cf]);                               \
  }
  for (int tt2 = 0; tt2 < 64; tt2 += 2) {
    if (tt2 + 2 < 64) {
      const int n2 = tt2 + 2;
      eA = *(const int4*)&gA[n2 * 32];
      eB = *(const int4*)&gB[(size_t)(n2 >> 1) * (kC * 64) + (n2 & 1) * 32];
    }
    FRAGS_MFMA(0);
    *(int4*)&As[1][srow][spos * 16] = oA;
    *(int4*)&Bs[1][srow][spos * 16] = oB;
    __syncthreads();
    if (tt2 + 3 < 64) {
      const int n3 = tt2 + 3;
      oA = *(const int4*)&gA[n3 * 32];
      oB = *(const int4*)&gB[(size_t)(n3 >> 1) * (kC * 64) + (n3 & 1) * 32];
    }
    FRAGS_MFMA(1);
    if (tt2 + 2 < 64) {
      *(int4*)&As[0][srow][spos * 16] = eA;
      *(int4*)&Bs[0][srow][spos * 16] = eB;
    }
    __syncthreads();
  }
#undef FRAGS_MFMA
  // epilogue: h = x - x_r; per-wave LDS transpose (alias smem) -> hT[m][c]
  bf16* bncw = ((bf16*)smem) + w * 16 * 72;
#pragma unroll
  for (int mf = 0; mf < 4; mf++) {
    const int mbase = m0 + mh * 64 + mf * 16;
    float hh[4][4];
#pragma unroll
    for (int cf = 0; cf < 4; cf++) {
      const int c = c0 + ch * 64 + cf * 16 + lo4;
      const f32x4 xval =
          *(const f32x4*)&x[((size_t)(b * kC + c)) * kN + mbase + g * 4];
#pragma unroll
      for (int r = 0; r < 4; r++) hh[cf][r] = xval[r] - acc[mf][cf][r];
    }
#pragma unroll
    for (int cf = 0; cf < 4; cf++)
#pragma unroll
      for (int r = 0; r < 4; r++)
        bncw[(4 * g + r) * 72 + cf * 16 + lo4] = (bf16)hh[cf][r];
    {
      const int rr = l >> 2, seg = (l & 3) * 16;
      const bf16x8 v0 = *(const bf16x8*)&bncw[rr * 72 + seg];
      const bf16x8 v1 = *(const bf16x8*)&bncw[rr * 72 + seg + 8];
      bf16* orow =
          &hT[((size_t)(b * kN + mbase + rr)) * kC + c0 + ch * 64 + seg];
      *(bf16x8*)&orow[0] = v0;
      *(bf16x8*)&orow[8] = v1;
    }
  }
}

// -------- final: D[n][c] = hT[n][k] wt[c][k]; BN+ReLU+residual
__global__ __launch_bounds__(256, 2) void k_final(
    const bf16* __restrict__ hT, const bf16* __restrict__ wt_bf,
    const float* __restrict__ x, const float* __restrict__ bt,
    const float* __restrict__ beta, const float* __restrict__ rmean,
    const float* __restrict__ invg, float* __restrict__ out) {
  __shared__ __align__(16) bf16 As[2][128][32];
  __shared__ __align__(16) bf16 Bs[2][128][32];
  const int blk = blockIdx.x;  // 512 = 8b x (16nb x 4cb)
  const int b = blk & 7, tile = blk >> 3;
  const int cb = tile & 3, nb = tile >> 2;
  const int n0 = nb * 128, c0 = cb * 128;
  const int t_ = threadIdx.x, w = t_ >> 6, l = t_ & 63, lo4 = l & 15, g = l >> 4;
  const int mh = w >> 1, ch = w & 1;
  const int srow = w * 16 + (l >> 2), sch = l & 3;
  const int spos = sch ^ ((l >> 3) & 3);
  const int rpos = g ^ ((lo4 >> 1) & 3);
  const bf16* gA0 = &hT[((size_t)(b * kN + n0 + srow)) * kC + sch * 8];
  const bf16* gA1 = gA0 + (size_t)64 * kC;
  const bf16* gB0 = &wt_bf[(size_t)(c0 + srow) * kC + sch * 8];
  const bf16* gB1 = gB0 + (size_t)64 * kC;
  f32x4 acc[4][4] = {};
  bf16x8 ra0, ra1, rb0, rb1;
  ra0 = *(const bf16x8*)&gA0[0];
  ra1 = *(const bf16x8*)&gA1[0];
  rb0 = *(const bf16x8*)&gB0[0];
  rb1 = *(const bf16x8*)&gB1[0];
  *(bf16x8*)&As[0][srow][spos * 8] = ra0;
  *(bf16x8*)&As[0][srow + 64][spos * 8] = ra1;
  *(bf16x8*)&Bs[0][srow][spos * 8] = rb0;
  *(bf16x8*)&Bs[0][srow + 64][spos * 8] = rb1;
  __syncthreads();
  for (int tt = 0; tt < 16; tt++) {
    const int buf = tt & 1;
    if (tt < 15) {
      const int k0 = (tt + 1) * 32;
      ra0 = *(const bf16x8*)&gA0[k0];
      ra1 = *(const bf16x8*)&gA1[k0];
      rb0 = *(const bf16x8*)&gB0[k0];
      rb1 = *(const bf16x8*)&gB1[k0];
    }
    bf16x8 af[4], bfr[4];
#pragma unroll
    for (int nf = 0; nf < 4; nf++)
      af[nf] = *(const bf16x8*)&As[buf][mh * 64 + nf * 16 + lo4][rpos * 8];
#pragma unroll
    for (int cf = 0; cf < 4; cf++)
      bfr[cf] = *(const bf16x8*)&Bs[buf][ch * 64 + cf * 16 + lo4][rpos * 8];
#pragma unroll
    for (int nf = 0; nf < 4; nf++)
#pragma unroll
      for (int cf = 0; cf < 4; cf++)
        acc[nf][cf] = MFMA16(af[nf], bfr[cf], acc[nf][cf]);
    if (tt < 15) {
      *(bf16x8*)&As[buf ^ 1][srow][spos * 8] = ra0;
      *(bf16x8*)&As[buf ^ 1][srow + 64][spos * 8] = ra1;
      *(bf16x8*)&Bs[buf ^ 1][srow][spos * 8] = rb0;
      *(bf16x8*)&Bs[buf ^ 1][srow + 64][spos * 8] = rb1;
    }
    __syncthreads();
  }
#pragma unroll
  for (int cf = 0; cf < 4; cf++) {
    const int c = c0 + ch * 64 + cf * 16 + lo4;
    const float btv = bt[c], rmv = rmean[c], igv = invg[c], bev = beta[c];
#pragma unroll
    for (int nf = 0; nf < 4; nf++) {
      const int nbase = n0 + mh * 64 + nf * 16 + g * 4;
      const size_t base = ((size_t)(b * kC + c)) * kN + nbase;
      const f32x4 xval = *(const f32x4*)&x[base];
      f32x4 o;
#pragma unroll
      for (int r = 0; r < 4; r++) {
        float v = (acc[nf][cf][r] + btv - rmv) * igv + bev;
        v = fmaxf(v, 0.0f);
        o[r] = xval[r] + v;
      }
      *(f32x4*)&out[base] = o;
    }
  }
}

extern "C" void kernel_launch(void* const* d_in, const int* in_sizes, int n_in,
                              void* d_out, int out_size, void* d_ws,
                              size_t ws_size, hipStream_t stream) {
  const float* x = (const float*)d_in[0];
  const float* query = (const float*)d_in[1];
  const int* mask = (const int*)d_in[2];
  const float* wqk = (const float*)d_in[3];
  const float* wv = (const float*)d_in[4];
  const float* bv = (const float*)d_in[5];
  const float* wt = (const float*)d_in[6];
  const float* bt = (const float*)d_in[7];
  const float* gamma = (const float*)d_in[8];
  const float* beta = (const float*)d_in[9];
  const float* rmean = (const float*)d_in[10];
  const float* rvar = (const float*)d_in[11];
  float* out = (float*)d_out;
  char* wsb = (char*)d_ws;

  const size_t MB = 1024 * 1024;
  unsigned char* UT8 = (unsigned char*)wsb;     // 32 MB [b][m][n] fp8
  bf16* trbufQ = (bf16*)wsb;                    // 16 MB (UT8 dead zone)
  bf16* trbufX = (bf16*)(wsb + 16 * MB);        // 16 MB (UT8 dead zone)
  bf16* xv2 = (bf16*)(wsb + 32 * MB);           // 16 MB bf16 tiled
  unsigned* xv8 = (unsigned*)(wsb + 48 * MB);   // 8 MB fp8 tiled
  bf16* hT = (bf16*)(wsb + 56 * MB);            // 8 MB [b][n][c]
  bf16* qT = (bf16*)(wsb + 64 * MB);            // 4 MB
  bf16* kT = (bf16*)(wsb + 68 * MB);            // 4 MB
  bf16* wqk_bf = (bf16*)(wsb + 72 * MB);        // 128 KB
  bf16* wv_bf = wqk_bf + 65536;                 // 512 KB
  bf16* wt_bf = wv_bf + 262144;                 // 512 KB
  float* invg = (float*)(wt_bf + 262144);       // 2 KB
  float* Ssum = invg + 512;                     // 64 KB (becomes invS)
  float* cnt = Ssum + kB * kN;                  // 32 B

  k_prep<<<136, 256, 0, stream>>>(mask, wqk, wv, wt, gamma, rvar, cnt, wqk_bf,
                                  wv_bf, wt_bf, invg, Ssum);
  k_tr2<<<dim3(kN / 64, kC / 32, 16), 256, 0, stream>>>(query, x, trbufQ,
                                                        trbufX);
  k_projQK<<<dim3(16, kB, 2), 256, 0, stream>>>(trbufQ, trbufX, wqk_bf, qT,
                                                kT);
  k_projV<<<512, 256, 0, stream>>>(trbufX, wv_bf, bv, xv2);
  k_sum<<<512, 256, 0, stream>>>(qT, kT, mask, cnt, UT8, Ssum);
  k_invs<<<64, 256, 0, stream>>>(Ssum);
  k_scale<<<1024, 256, 0, stream>>>(xv2, Ssum, xv8);
  k_attn2<<<512, 256, 0, stream>>>(UT8, (const unsigned char*)xv8, x, hT);
  k_final<<<512, 256, 0, stream>>>(hT, wt_bf, x, bt, beta, rmean, invg, out);
}

// Round 17
// 152.009 us; speedup vs baseline: 1.1838x; 1.0128x over previous
//
#include <hip/hip_runtime.h>
#include <math.h>

typedef __bf16 bf16;
typedef bf16 bf16x8 __attribute__((ext_vector_type(8)));
typedef bf16 bf16x4 __attribute__((ext_vector_type(4)));
typedef float f32x4 __attribute__((ext_vector_type(4)));

constexpr int kB = 8, kC = 512, kC4 = 128, kN = 2048;

#define MFMA16(a, b, c) __builtin_amdgcn_mfma_f32_16x16x32_bf16(a, b, c, 0, 0, 0)
#define MFMA8(a, b, c) \
  __builtin_amdgcn_mfma_f32_16x16x32_fp8_fp8(a, b, c, 0, 0, 0)

__device__ __forceinline__ unsigned pack4_fp8(float a, float b, float c,
                                              float d) {
  unsigned v = 0;
  v = __builtin_amdgcn_cvt_pk_fp8_f32(a, b, v, false);
  v = __builtin_amdgcn_cvt_pk_fp8_f32(c, d, v, true);
  return v;
}

// ---------------------------------------------------------------- prep
__global__ __launch_bounds__(256) void k_prep(
    const int* __restrict__ mask, const float* __restrict__ wqk,
    const float* __restrict__ wv, const float* __restrict__ wt,
    const float* __restrict__ gamma, const float* __restrict__ rvar,
    float* __restrict__ cnt, bf16* __restrict__ wqk_bf,
    bf16* __restrict__ wv_bf, bf16* __restrict__ wt_bf,
    float* __restrict__ invg, float* __restrict__ Ssum) {
  const int t = threadIdx.x;
  if (blockIdx.x < 8) {
    const int b = blockIdx.x;
    int s = 0;
    for (int i = t; i < kN; i += 256) s += mask[b * kN + i];
    __shared__ int red[256];
    red[t] = s;
    __syncthreads();
    for (int off = 128; off > 0; off >>= 1) {
      if (t < off) red[t] += red[t + off];
      __syncthreads();
    }
    if (t == 0) cnt[b] = (float)red[0];
    return;
  }
  const int total = 65536 + 262144 + 262144 + 512 + 16384;
  for (int i = (blockIdx.x - 8) * 256 + t; i < total; i += 128 * 256) {
    if (i < 65536) {
      wqk_bf[i] = (bf16)wqk[i];
    } else if (i < 327680) {
      wv_bf[i - 65536] = (bf16)wv[i - 65536];
    } else if (i < 589824) {
      wt_bf[i - 327680] = (bf16)wt[i - 327680];
    } else if (i < 590336) {
      const int j = i - 589824;
      invg[j] = gamma[j] * rsqrtf(rvar[j] + 1e-5f);
    } else {
      Ssum[i - 590336] = 0.0f;
    }
  }
}

// ---------------- transpose+convert both inputs: [C][N] f32 -> [N][C] bf16
__global__ __launch_bounds__(256) void k_tr2(const float* __restrict__ Q,
                                             const float* __restrict__ X,
                                             bf16* __restrict__ XTq,
                                             bf16* __restrict__ XTx) {
  __shared__ float tile[32][69];
  const int z = blockIdx.z, b = z & 7;
  const float* Xs = (z < 8) ? Q : X;
  bf16* XT = (z < 8) ? XTq : XTx;
  const int c0 = blockIdx.y * 32, n0 = blockIdx.x * 64;
  const int t = threadIdx.x;
  const int cc = t >> 4, n4 = (t & 15) * 4;
#pragma unroll
  for (int p = 0; p < 2; p++) {
    const int c = p * 16 + cc;
    const f32x4 v =
        *(const f32x4*)&Xs[((size_t)(b * kC + c0 + c)) * kN + n0 + n4];
    tile[c][n4 + 0] = v[0];
    tile[c][n4 + 1] = v[1];
    tile[c][n4 + 2] = v[2];
    tile[c][n4 + 3] = v[3];
  }
  __syncthreads();
  const int n = t >> 2, c8 = (t & 3) * 8;
  bf16x8 o;
#pragma unroll
  for (int j = 0; j < 8; j++) o[j] = (bf16)tile[c8 + j][n];
  *(bf16x8*)&XT[((size_t)(b * kN + n0 + n)) * kC + c0 + c8] = o;
}

// -------- q/k projections (staged GEMM): OT[b][n][128] = (wqk @ src)^T
__global__ __launch_bounds__(256, 2) void k_projQK(
    const bf16* __restrict__ XTq, const bf16* __restrict__ XTx,
    const bf16* __restrict__ W, bf16* __restrict__ qT, bf16* __restrict__ kT) {
  __shared__ __align__(16) bf16 As[2][128][32];
  __shared__ __align__(16) bf16 Bs[2][128][32];
  const int nb = blockIdx.x, b = blockIdx.y, src = blockIdx.z;
  const bf16* XT = src ? XTx : XTq;
  bf16* OT = src ? kT : qT;
  const int n0 = nb * 128;
  const int t_ = threadIdx.x, w = t_ >> 6, l = t_ & 63, lo4 = l & 15, g = l >> 4;
  const int mh = w >> 1, ch = w & 1;
  const int srow = w * 16 + (l >> 2), sch = l & 3;
  const int spos = sch ^ ((l >> 3) & 3);
  const int rpos = g ^ ((lo4 >> 1) & 3);
  const bf16* gA0 = &XT[((size_t)(b * kN + n0 + srow)) * kC + sch * 8];
  const bf16* gA1 = gA0 + (size_t)64 * kC;
  const bf16* gB0 = &W[(size_t)srow * kC + sch * 8];
  const bf16* gB1 = gB0 + (size_t)64 * kC;
  f32x4 acc[4][4] = {};
  bf16x8 ra0, ra1, rb0, rb1;
  ra0 = *(const bf16x8*)&gA0[0];
  ra1 = *(const bf16x8*)&gA1[0];
  rb0 = *(const bf16x8*)&gB0[0];
  rb1 = *(const bf16x8*)&gB1[0];
  *(bf16x8*)&As[0][srow][spos * 8] = ra0;
  *(bf16x8*)&As[0][srow + 64][spos * 8] = ra1;
  *(bf16x8*)&Bs[0][srow][spos * 8] = rb0;
  *(bf16x8*)&Bs[0][srow + 64][spos * 8] = rb1;
  __syncthreads();
  for (int tt = 0; tt < 16; tt++) {
    const int buf = tt & 1;
    if (tt < 15) {
      const int k0 = (tt + 1) * 32;
      ra0 = *(const bf16x8*)&gA0[k0];
      ra1 = *(const bf16x8*)&gA1[k0];
      rb0 = *(const bf16x8*)&gB0[k0];
      rb1 = *(const bf16x8*)&gB1[k0];
    }
    bf16x8 af[4], bfr[4];
#pragma unroll
    for (int nf = 0; nf < 4; nf++)
      af[nf] = *(const bf16x8*)&As[buf][mh * 64 + nf * 16 + lo4][rpos * 8];
#pragma unroll
    for (int cf = 0; cf < 4; cf++)
      bfr[cf] = *(const bf16x8*)&Bs[buf][ch * 64 + cf * 16 + lo4][rpos * 8];
#pragma unroll
    for (int nf = 0; nf < 4; nf++)
#pragma unroll
      for (int cf = 0; cf < 4; cf++)
        acc[nf][cf] = MFMA16(af[nf], bfr[cf], acc[nf][cf]);
    if (tt < 15) {
      *(bf16x8*)&As[buf ^ 1][srow][spos * 8] = ra0;
      *(bf16x8*)&As[buf ^ 1][srow + 64][spos * 8] = ra1;
      *(bf16x8*)&Bs[buf ^ 1][srow][spos * 8] = rb0;
      *(bf16x8*)&Bs[buf ^ 1][srow + 64][spos * 8] = rb1;
    }
    __syncthreads();
  }
  bf16* bncw = ((bf16*)As) + w * 16 * 72;
#pragma unroll
  for (int nf = 0; nf < 4; nf++) {
    const int nbase = n0 + mh * 64 + nf * 16;
#pragma unroll
    for (int cf = 0; cf < 4; cf++)
#pragma unroll
      for (int r = 0; r < 4; r++)
        bncw[(4 * g + r) * 72 + cf * 16 + lo4] = (bf16)acc[nf][cf][r];
    const int rr = l >> 2, seg = (l & 3) * 16;
    const bf16x8 v0 = *(const bf16x8*)&bncw[rr * 72 + seg];
    const bf16x8 v1 = *(const bf16x8*)&bncw[rr * 72 + seg + 8];
    bf16* orow = &OT[((size_t)(b * kN + nbase + rr)) * kC4 + ch * 64 + seg];
    *(bf16x8*)&orow[0] = v0;
    *(bf16x8*)&orow[8] = v1;
  }
}

// -------- value projection (staged GEMM) -> TILED xv2[b][n>>6][c][n&63]
__global__ __launch_bounds__(256, 2) void k_projV(
    const bf16* __restrict__ XTx, const bf16* __restrict__ Wv,
    const float* __restrict__ bv, bf16* __restrict__ xv2) {
  __shared__ __align__(16) bf16 As[2][128][32];
  __shared__ __align__(16) bf16 Bs[2][128][32];
  const int blk = blockIdx.x;  // 512 = 8b x (16nb x 4cb)
  const int b = blk & 7, tile = blk >> 3;
  const int cb = tile & 3, nb = tile >> 2;
  const int n0 = nb * 128, c0 = cb * 128;
  const int t_ = threadIdx.x, w = t_ >> 6, l = t_ & 63, lo4 = l & 15, g = l >> 4;
  const int mh = w >> 1, ch = w & 1;
  const int srow = w * 16 + (l >> 2), sch = l & 3;
  const int spos = sch ^ ((l >> 3) & 3);
  const int rpos = g ^ ((lo4 >> 1) & 3);
  const bf16* gA0 = &XTx[((size_t)(b * kN + n0 + srow)) * kC + sch * 8];
  const bf16* gA1 = gA0 + (size_t)64 * kC;
  const bf16* gB0 = &Wv[(size_t)(c0 + srow) * kC + sch * 8];
  const bf16* gB1 = gB0 + (size_t)64 * kC;
  f32x4 acc[4][4] = {};
  bf16x8 ra0, ra1, rb0, rb1;
  ra0 = *(const bf16x8*)&gA0[0];
  ra1 = *(const bf16x8*)&gA1[0];
  rb0 = *(const bf16x8*)&gB0[0];
  rb1 = *(const bf16x8*)&gB1[0];
  *(bf16x8*)&As[0][srow][spos * 8] = ra0;
  *(bf16x8*)&As[0][srow + 64][spos * 8] = ra1;
  *(bf16x8*)&Bs[0][srow][spos * 8] = rb0;
  *(bf16x8*)&Bs[0][srow + 64][spos * 8] = rb1;
  __syncthreads();
  for (int tt = 0; tt < 16; tt++) {
    const int buf = tt & 1;
    if (tt < 15) {
      const int k0 = (tt + 1) * 32;
      ra0 = *(const bf16x8*)&gA0[k0];
      ra1 = *(const bf16x8*)&gA1[k0];
      rb0 = *(const bf16x8*)&gB0[k0];
      rb1 = *(const bf16x8*)&gB1[k0];
    }
    bf16x8 af[4], bfr[4];
#pragma unroll
    for (int nf = 0; nf < 4; nf++)
      af[nf] = *(const bf16x8*)&As[buf][mh * 64 + nf * 16 + lo4][rpos * 8];
#pragma unroll
    for (int cf = 0; cf < 4; cf++)
      bfr[cf] = *(const bf16x8*)&Bs[buf][ch * 64 + cf * 16 + lo4][rpos * 8];
#pragma unroll
    for (int nf = 0; nf < 4; nf++)
#pragma unroll
      for (int cf = 0; cf < 4; cf++)
        acc[nf][cf] = MFMA16(af[nf], bfr[cf], acc[nf][cf]);
    if (tt < 15) {
      *(bf16x8*)&As[buf ^ 1][srow][spos * 8] = ra0;
      *(bf16x8*)&As[buf ^ 1][srow + 64][spos * 8] = ra1;
      *(bf16x8*)&Bs[buf ^ 1][srow][spos * 8] = rb0;
      *(bf16x8*)&Bs[buf ^ 1][srow + 64][spos * 8] = rb1;
    }
    __syncthreads();
  }
#pragma unroll
  for (int cf = 0; cf < 4; cf++) {
    const int c = c0 + ch * 64 + cf * 16 + lo4;
    const float bvv = bv[c];
#pragma unroll
    for (int nf = 0; nf < 4; nf++) {
      const int nbase = n0 + mh * 64 + nf * 16 + g * 4;
      bf16x4 o;
#pragma unroll
      for (int r = 0; r < 4; r++) o[r] = (bf16)(acc[nf][cf][r] + bvv);
      *(bf16x4*)&xv2[(((size_t)b * 32 + (nbase >> 6)) * kC + c) * 64 +
                     (nbase & 63)] = o;
    }
  }
}

// ---------------- pass 1: U^T[m][n] exp-factors -> fp8 UT8; partial S[n].
__global__ __launch_bounds__(256) void k_sum(
    const bf16* __restrict__ qT, const bf16* __restrict__ kT,
    const int* __restrict__ mask, const float* __restrict__ cnt,
    unsigned char* __restrict__ UT8, float* __restrict__ Ssum) {
  __shared__ __align__(16) bf16 kts[2][64][128];
  __shared__ __align__(16) unsigned Ubuf[64][16];
  __shared__ int mss[2][64];
  const int blk = blockIdx.x;
  const int b = blk & 7, nb = (blk >> 3) & 31, mh2 = blk >> 8;
  const int m00 = mh2 * 1024;
  const int t_ = threadIdx.x, w = t_ >> 6, l = t_ & 63, lo4 = l & 15, g = l >> 4;
  const float invd = 1.0f / (cnt[b] + 1e-9f);
  const int n0 = nb * 64;
  bf16x8 aq[4];
#pragma unroll
  for (int ks = 0; ks < 4; ks++)
    aq[ks] = *(const bf16x8*)&qT[((size_t)(b * kN + n0 + w * 16 + lo4)) * kC4 +
                                 ks * 32 + g * 8];
  const int nq = n0 + w * 16 + g * 4;
  const int4 mi = *(const int4*)&mask[b * kN + nq];
  const int mn4[4] = {mi.x, mi.y, mi.z, mi.w};
  float rs4[4] = {0.0f, 0.0f, 0.0f, 0.0f};
  bf16x8 rg[4];
#pragma unroll
  for (int i = 0; i < 4; i++) {
    const int row = w * 16 + i * 4 + g;
    const int q = (l & 15) ^ (row & 7);
    rg[i] = *(const bf16x8*)&kT[((size_t)(b * kN + m00 + row)) * kC4 + q * 8];
  }
#pragma unroll
  for (int i = 0; i < 4; i++) {
    const int row = w * 16 + i * 4 + g;
    *(bf16x8*)&kts[0][row][(l & 15) * 8] = rg[i];
  }
  if (t_ < 16)
    *(int4*)&mss[0][t_ * 4] = *(const int4*)&mask[b * kN + m00 + t_ * 4];
  __syncthreads();
  for (int tt = 0; tt < 16; tt++) {
    const int buf = tt & 1;
    if (tt < 15) {
      const int m0 = m00 + (tt + 1) * 64;
#pragma unroll
      for (int i = 0; i < 4; i++) {
        const int row = w * 16 + i * 4 + g;
        const int q = (l & 15) ^ (row & 7);
        rg[i] = *(const bf16x8*)&kT[((size_t)(b * kN + m0 + row)) * kC4 + q * 8];
      }
    }
#pragma unroll
    for (int mf = 0; mf < 4; mf++) {
      f32x4 e = {};
#pragma unroll
      for (int ks = 0; ks < 4; ks++) {
        const bf16x8 bk =
            *(const bf16x8*)&kts[buf][mf * 16 + lo4]
                                 [((ks * 4 + g) ^ (lo4 & 7)) * 8];
        e = MFMA16(aq[ks], bk, e);
      }
      const int mmv = mss[buf][mf * 16 + lo4];
      float u[4];
#pragma unroll
      for (int r = 0; r < 4; r++) {
        u[r] = mmv ? (mn4[r] ? __expf(e[r] * invd) : 1.0f) : 0.0f;
        rs4[r] += u[r];
      }
      Ubuf[mf * 16 + lo4][(w * 4 + g) ^ lo4] =
          pack4_fp8(u[0], u[1], u[2], u[3]);
    }
    __syncthreads();
    if (tt < 15) {
#pragma unroll
      for (int i = 0; i < 4; i++) {
        const int row = w * 16 + i * 4 + g;
        *(bf16x8*)&kts[buf ^ 1][row][(l & 15) * 8] = rg[i];
      }
      if (t_ < 16)
        *(int4*)&mss[buf ^ 1][t_ * 4] =
            *(const int4*)&mask[b * kN + m00 + (tt + 1) * 64 + t_ * 4];
    }
    {
      const int row = t_ >> 2, q = t_ & 3;
      int4 pkt;
      pkt.x = (int)Ubuf[row][(q * 4 + 0) ^ (row & 15)];
      pkt.y = (int)Ubuf[row][(q * 4 + 1) ^ (row & 15)];
      pkt.z = (int)Ubuf[row][(q * 4 + 2) ^ (row & 15)];
      pkt.w = (int)Ubuf[row][(q * 4 + 3) ^ (row & 15)];
      *(int4*)&UT8[((size_t)(b * kN + m00 + tt * 64 + row)) * kN + n0 +
                   q * 16] = pkt;
    }
    __syncthreads();
  }
#pragma unroll
  for (int r = 0; r < 4; r++) {
#pragma unroll
    for (int off = 1; off < 16; off <<= 1) rs4[r] += __shfl_xor(rs4[r], off);
  }
  if (lo4 == 0) {
#pragma unroll
    for (int r = 0; r < 4; r++) atomicAdd(&Ssum[b * kN + nq + r], rs4[r]);
  }
}

// ---------------- xv2 (bf16 tiled) * (1/Ssum[n]) -> xv8 (fp8 tiled)
__global__ __launch_bounds__(256) void k_scale(const bf16* __restrict__ xv2,
                                               const float* __restrict__ Ssum,
                                               unsigned* __restrict__ xv8) {
  const int blk = blockIdx.x;  // 1024 = 8b x 128 parts
  const int b = blk & 7, part = blk >> 3;
  const size_t base = (size_t)b * (32 * kC * 64);
  for (int it = 0; it < 4; it++) {
    const int chunk = part * 1024 + it * 256 + threadIdx.x;
    const size_t e = (size_t)chunk * 8;
    const int n = ((int)(e >> 15)) * 64 + ((int)e & 63);
    const bf16x8 v = *(const bf16x8*)&xv2[base + e];
    const f32x4 ss0 = *(const f32x4*)&Ssum[b * kN + n];
    const f32x4 ss1 = *(const f32x4*)&Ssum[b * kN + n + 4];
    f32x4 s0, s1;
#pragma unroll
    for (int j = 0; j < 4; j++) {
      s0[j] = 1.0f / ss0[j];
      s1[j] = 1.0f / ss1[j];
    }
    uint2 o;
    o.x = pack4_fp8((float)v[0] * s0[0], (float)v[1] * s0[1],
                    (float)v[2] * s0[2], (float)v[3] * s0[3]);
    o.y = pack4_fp8((float)v[4] * s1[0], (float)v[5] * s1[1],
                    (float)v[6] * s1[2], (float)v[7] * s1[3]);
    *(uint2*)&xv8[(base + e) >> 2] = o;
  }
}

// -------- pass 2 (fp8): x_r^T[m][c] = sum_n UT8[m][n]*xv8[c][n]; h=x-x_r
// 128m x 128c, 4 waves, depth-2 reg pipeline; CONFLICT-FREE 8B XOR swizzle:
// LDS unit v = u ^ ((row>>2)&3); write = one int4 at slot ps^((row>>3)&1)
// with halves swapped when (row>>2)&1; read pos = g ^ ((lo4>>2)&3).
__global__ __launch_bounds__(256, 2) void k_attn2(
    const unsigned char* __restrict__ UT8, const unsigned char* __restrict__ xv8,
    const float* __restrict__ x, bf16* __restrict__ hT) {
  __shared__ __align__(16) unsigned char smem[16384];
  unsigned char (*As)[128][32] = (unsigned char (*)[128][32])smem;
  unsigned char (*Bs)[128][32] = (unsigned char (*)[128][32])(smem + 8192);
  const int blk = blockIdx.x;  // 512 = 8b x (16mb x 4cb)
  const int b = blk & 7, tile = blk >> 3;
  const int cb = tile & 3, mb = tile >> 2;
  const int m0 = mb * 128, c0 = cb * 128;
  const int t_ = threadIdx.x, w = t_ >> 6, l = t_ & 63, lo4 = l & 15, g = l >> 4;
  const int mh = w >> 1, ch = w & 1;
  const int srow = t_ >> 1, ps = t_ & 1;
  const int m16 = (ps ^ ((srow >> 3) & 1)) * 16;  // 16B slot
  const int hsw = (srow >> 2) & 1;                // swap 8B halves?
  const int rp8 = (lo4 >> 2) & 3;                 // read-pos xor key
  const unsigned char* gA = &UT8[((size_t)(b * kN + m0 + srow)) * kN + ps * 16];
  const unsigned char* gB =
      &xv8[(((size_t)b * 32) * kC + c0 + srow) * 64 + ps * 16];
  f32x4 acc[4][4] = {};
#define STORE_TILE(BUF, VA, VB)                                                \
  {                                                                            \
    int4 sa = VA, sb = VB;                                                     \
    if (hsw) {                                                                 \
      sa.x = (VA).z; sa.y = (VA).w; sa.z = (VA).x; sa.w = (VA).y;              \
      sb.x = (VB).z; sb.y = (VB).w; sb.z = (VB).x; sb.w = (VB).y;              \
    }                                                                          \
    *(int4*)&As[BUF][srow][m16] = sa;                                          \
    *(int4*)&Bs[BUF][srow][m16] = sb;                                          \
  }
  {
    const int4 a = *(const int4*)&gA[0];
    const int4 bb = *(const int4*)&gB[0];
    STORE_TILE(0, a, bb);
  }
  int4 oA, oB, eA, eB;
  oA = *(const int4*)&gA[32];
  oB = *(const int4*)&gB[32];
  __syncthreads();
#define FRAGS_MFMA(BUF)                                                        \
  {                                                                            \
    long af[4], bfr[4];                                                        \
    _Pragma("unroll") for (int mf = 0; mf < 4; mf++) {                         \
      const int row = mh * 64 + mf * 16 + lo4;                                 \
      af[mf] = *(const long*)&As[BUF][row][(g ^ rp8) * 8];                     \
    }                                                                          \
    _Pragma("unroll") for (int cf = 0; cf < 4; cf++) {                         \
      const int row = ch * 64 + cf * 16 + lo4;                                 \
      bfr[cf] = *(const long*)&Bs[BUF][row][(g ^ rp8) * 8];                    \
    }                                                                          \
    _Pragma("unroll") for (int mf = 0; mf < 4; mf++)                           \
        _Pragma("unroll") for (int cf = 0; cf < 4; cf++) acc[mf][cf] =         \
            MFMA8(af[mf], bfr[cf], acc[mf][cf]);                               \
  }
  for (int tt2 = 0; tt2 < 64; tt2 += 2) {
    if (tt2 + 2 < 64) {
      const int n2 = tt2 + 2;
      eA = *(const int4*)&gA[n2 * 32];
      eB = *(const int4*)&gB[(size_t)(n2 >> 1) * (kC * 64) + (n2 & 1) * 32];
    }
    FRAGS_MFMA(0);
    STORE_TILE(1, oA, oB);
    __syncthreads();
    if (tt2 + 3 < 64) {
      const int n3 = tt2 + 3;
      oA = *(const int4*)&gA[n3 * 32];
      oB = *(const int4*)&gB[(size_t)(n3 >> 1) * (kC * 64) + (n3 & 1) * 32];
    }
    FRAGS_MFMA(1);
    if (tt2 + 2 < 64) {
      STORE_TILE(0, eA, eB);
    }
    __syncthreads();
  }
#undef FRAGS_MFMA
#undef STORE_TILE
  // epilogue: h = x - x_r; per-wave LDS transpose (alias smem) -> hT[m][c]
  bf16* bncw = ((bf16*)smem) + w * 16 * 72;
#pragma unroll
  for (int mf = 0; mf < 4; mf++) {
    const int mbase = m0 + mh * 64 + mf * 16;
    float hh[4][4];
#pragma unroll
    for (int cf = 0; cf < 4; cf++) {
      const int c = c0 + ch * 64 + cf * 16 + lo4;
      const f32x4 xval =
          *(const f32x4*)&x[((size_t)(b * kC + c)) * kN + mbase + g * 4];
#pragma unroll
      for (int r = 0; r < 4; r++) hh[cf][r] = xval[r] - acc[mf][cf][r];
    }
#pragma unroll
    for (int cf = 0; cf < 4; cf++)
#pragma unroll
      for (int r = 0; r < 4; r++)
        bncw[(4 * g + r) * 72 + cf * 16 + lo4] = (bf16)hh[cf][r];
    {
      const int rr = l >> 2, seg = (l & 3) * 16;
      const bf16x8 v0 = *(const bf16x8*)&bncw[rr * 72 + seg];
      const bf16x8 v1 = *(const bf16x8*)&bncw[rr * 72 + seg + 8];
      bf16* orow =
          &hT[((size_t)(b * kN + mbase + rr)) * kC + c0 + ch * 64 + seg];
      *(bf16x8*)&orow[0] = v0;
      *(bf16x8*)&orow[8] = v1;
    }
  }
}

// -------- final: D[n][c] = hT[n][k] wt[c][k]; BN+ReLU+residual
__global__ __launch_bounds__(256, 2) void k_final(
    const bf16* __restrict__ hT, const bf16* __restrict__ wt_bf,
    const float* __restrict__ x, const float* __restrict__ bt,
    const float* __restrict__ beta, const float* __restrict__ rmean,
    const float* __restrict__ invg, float* __restrict__ out) {
  __shared__ __align__(16) bf16 As[2][128][32];
  __shared__ __align__(16) bf16 Bs[2][128][32];
  const int blk = blockIdx.x;  // 512 = 8b x (16nb x 4cb)
  const int b = blk & 7, tile = blk >> 3;
  const int cb = tile & 3, nb = tile >> 2;
  const int n0 = nb * 128, c0 = cb * 128;
  const int t_ = threadIdx.x, w = t_ >> 6, l = t_ & 63, lo4 = l & 15, g = l >> 4;
  const int mh = w >> 1, ch = w & 1;
  const int srow = w * 16 + (l >> 2), sch = l & 3;
  const int spos = sch ^ ((l >> 3) & 3);
  const int rpos = g ^ ((lo4 >> 1) & 3);
  const bf16* gA0 = &hT[((size_t)(b * kN + n0 + srow)) * kC + sch * 8];
  const bf16* gA1 = gA0 + (size_t)64 * kC;
  const bf16* gB0 = &wt_bf[(size_t)(c0 + srow) * kC + sch * 8];
  const bf16* gB1 = gB0 + (size_t)64 * kC;
  f32x4 acc[4][4] = {};
  bf16x8 ra0, ra1, rb0, rb1;
  ra0 = *(const bf16x8*)&gA0[0];
  ra1 = *(const bf16x8*)&gA1[0];
  rb0 = *(const bf16x8*)&gB0[0];
  rb1 = *(const bf16x8*)&gB1[0];
  *(bf16x8*)&As[0][srow][spos * 8] = ra0;
  *(bf16x8*)&As[0][srow + 64][spos * 8] = ra1;
  *(bf16x8*)&Bs[0][srow][spos * 8] = rb0;
  *(bf16x8*)&Bs[0][srow + 64][spos * 8] = rb1;
  __syncthreads();
  for (int tt = 0; tt < 16; tt++) {
    const int buf = tt & 1;
    if (tt < 15) {
      const int k0 = (tt + 1) * 32;
      ra0 = *(const bf16x8*)&gA0[k0];
      ra1 = *(const bf16x8*)&gA1[k0];
      rb0 = *(const bf16x8*)&gB0[k0];
      rb1 = *(const bf16x8*)&gB1[k0];
    }
    bf16x8 af[4], bfr[4];
#pragma unroll
    for (int nf = 0; nf < 4; nf++)
      af[nf] = *(const bf16x8*)&As[buf][mh * 64 + nf * 16 + lo4][rpos * 8];
#pragma unroll
    for (int cf = 0; cf < 4; cf++)
      bfr[cf] = *(const bf16x8*)&Bs[buf][ch * 64 + cf * 16 + lo4][rpos * 8];
#pragma unroll
    for (int nf = 0; nf < 4; nf++)
#pragma unroll
      for (int cf = 0; cf < 4; cf++)
        acc[nf][cf] = MFMA16(af[nf], bfr[cf], acc[nf][cf]);
    if (tt < 15) {
      *(bf16x8*)&As[buf ^ 1][srow][spos * 8] = ra0;
      *(bf16x8*)&As[buf ^ 1][srow + 64][spos * 8] = ra1;
      *(bf16x8*)&Bs[buf ^ 1][srow][spos * 8] = rb0;
      *(bf16x8*)&Bs[buf ^ 1][srow + 64][spos * 8] = rb1;
    }
    __syncthreads();
  }
#pragma unroll
  for (int cf = 0; cf < 4; cf++) {
    const int c = c0 + ch * 64 + cf * 16 + lo4;
    const float btv = bt[c], rmv = rmean[c], igv = invg[c], bev = beta[c];
#pragma unroll
    for (int nf = 0; nf < 4; nf++) {
      const int nbase = n0 + mh * 64 + nf * 16 + g * 4;
      const size_t base = ((size_t)(b * kC + c)) * kN + nbase;
      const f32x4 xval = *(const f32x4*)&x[base];
      f32x4 o;
#pragma unroll
      for (int r = 0; r < 4; r++) {
        float v = (acc[nf][cf][r] + btv - rmv) * igv + bev;
        v = fmaxf(v, 0.0f);
        o[r] = xval[r] + v;
      }
      *(f32x4*)&out[base] = o;
    }
  }
}

extern "C" void kernel_launch(void* const* d_in, const int* in_sizes, int n_in,
                              void* d_out, int out_size, void* d_ws,
                              size_t ws_size, hipStream_t stream) {
  const float* x = (const float*)d_in[0];
  const float* query = (const float*)d_in[1];
  const int* mask = (const int*)d_in[2];
  const float* wqk = (const float*)d_in[3];
  const float* wv = (const float*)d_in[4];
  const float* bv = (const float*)d_in[5];
  const float* wt = (const float*)d_in[6];
  const float* bt = (const float*)d_in[7];
  const float* gamma = (const float*)d_in[8];
  const float* beta = (const float*)d_in[9];
  const float* rmean = (const float*)d_in[10];
  const float* rvar = (const float*)d_in[11];
  float* out = (float*)d_out;
  char* wsb = (char*)d_ws;

  const size_t MB = 1024 * 1024;
  unsigned char* UT8 = (unsigned char*)wsb;     // 32 MB [b][m][n] fp8
  bf16* trbufQ = (bf16*)wsb;                    // 16 MB (UT8 dead zone)
  bf16* trbufX = (bf16*)(wsb + 16 * MB);        // 16 MB (UT8 dead zone)
  bf16* xv2 = (bf16*)(wsb + 32 * MB);           // 16 MB bf16 tiled
  unsigned* xv8 = (unsigned*)(wsb + 48 * MB);   // 8 MB fp8 tiled
  bf16* hT = (bf16*)(wsb + 56 * MB);            // 8 MB [b][n][c]
  bf16* qT = (bf16*)(wsb + 64 * MB);            // 4 MB
  bf16* kT = (bf16*)(wsb + 68 * MB);            // 4 MB
  bf16* wqk_bf = (bf16*)(wsb + 72 * MB);        // 128 KB
  bf16* wv_bf = wqk_bf + 65536;                 // 512 KB
  bf16* wt_bf = wv_bf + 262144;                 // 512 KB
  float* invg = (float*)(wt_bf + 262144);       // 2 KB
  float* Ssum = invg + 512;                     // 64 KB
  float* cnt = Ssum + kB * kN;                  // 32 B

  k_prep<<<136, 256, 0, stream>>>(mask, wqk, wv, wt, gamma, rvar, cnt, wqk_bf,
                                  wv_bf, wt_bf, invg, Ssum);
  k_tr2<<<dim3(kN / 64, kC / 32, 16), 256, 0, stream>>>(query, x, trbufQ,
                                                        trbufX);
  k_projQK<<<dim3(16, kB, 2), 256, 0, stream>>>(trbufQ, trbufX, wqk_bf, qT,
                                                kT);
  k_projV<<<512, 256, 0, stream>>>(trbufX, wv_bf, bv, xv2);
  k_sum<<<512, 256, 0, stream>>>(qT, kT, mask, cnt, UT8, Ssum);
  k_scale<<<1024, 256, 0, stream>>>(xv2, Ssum, xv8);
  k_attn2<<<512, 256, 0, stream>>>(UT8, (const unsigned char*)xv8, x, hT);
  k_final<<<512, 256, 0, stream>>>(hT, wt_bf, x, bt, beta, rmean, invg, out);
}

// Round 18
// 147.300 us; speedup vs baseline: 1.2216x; 1.0320x over previous
//
#include <hip/hip_runtime.h>
#include <math.h>

typedef __bf16 bf16;
typedef bf16 bf16x8 __attribute__((ext_vector_type(8)));
typedef bf16 bf16x4 __attribute__((ext_vector_type(4)));
typedef float f32x4 __attribute__((ext_vector_type(4)));
typedef unsigned long long u64;

constexpr int kB = 8, kC = 512, kC4 = 128, kN = 2048;

#define MFMA16(a, b, c) __builtin_amdgcn_mfma_f32_16x16x32_bf16(a, b, c, 0, 0, 0)
#define MFMA8(a, b, c) \
  __builtin_amdgcn_mfma_f32_16x16x32_fp8_fp8(a, b, c, 0, 0, 0)

__device__ __forceinline__ unsigned pack4_fp8(float a, float b, float c,
                                              float d) {
  unsigned v = 0;
  v = __builtin_amdgcn_cvt_pk_fp8_f32(a, b, v, false);
  v = __builtin_amdgcn_cvt_pk_fp8_f32(c, d, v, true);
  return v;
}

// ---------------------------------------------------------------- prep
__global__ __launch_bounds__(256) void k_prep(
    const int* __restrict__ mask, const float* __restrict__ wqk,
    const float* __restrict__ wv, const float* __restrict__ wt,
    const float* __restrict__ gamma, const float* __restrict__ rvar,
    float* __restrict__ cnt, bf16* __restrict__ wqk_bf,
    bf16* __restrict__ wv_bf, bf16* __restrict__ wt_bf,
    float* __restrict__ invg, float* __restrict__ Ssum) {
  const int t = threadIdx.x;
  if (blockIdx.x < 8) {
    const int b = blockIdx.x;
    int s = 0;
    for (int i = t; i < kN; i += 256) s += mask[b * kN + i];
    __shared__ int red[256];
    red[t] = s;
    __syncthreads();
    for (int off = 128; off > 0; off >>= 1) {
      if (t < off) red[t] += red[t + off];
      __syncthreads();
    }
    if (t == 0) cnt[b] = (float)red[0];
    return;
  }
  const int total = 65536 + 262144 + 262144 + 512 + 16384;
  for (int i = (blockIdx.x - 8) * 256 + t; i < total; i += 128 * 256) {
    if (i < 65536) {
      wqk_bf[i] = (bf16)wqk[i];
    } else if (i < 327680) {
      wv_bf[i - 65536] = (bf16)wv[i - 65536];
    } else if (i < 589824) {
      wt_bf[i - 327680] = (bf16)wt[i - 327680];
    } else if (i < 590336) {
      const int j = i - 589824;
      invg[j] = gamma[j] * rsqrtf(rvar[j] + 1e-5f);
    } else {
      Ssum[i - 590336] = 0.0f;
    }
  }
}

// ---------------- transpose+convert both inputs: [C][N] f32 -> [N][C] bf16
__global__ __launch_bounds__(256) void k_tr2(const float* __restrict__ Q,
                                             const float* __restrict__ X,
                                             bf16* __restrict__ XTq,
                                             bf16* __restrict__ XTx) {
  __shared__ float tile[32][69];
  const int z = blockIdx.z, b = z & 7;
  const float* Xs = (z < 8) ? Q : X;
  bf16* XT = (z < 8) ? XTq : XTx;
  const int c0 = blockIdx.y * 32, n0 = blockIdx.x * 64;
  const int t = threadIdx.x;
  const int cc = t >> 4, n4 = (t & 15) * 4;
#pragma unroll
  for (int p = 0; p < 2; p++) {
    const int c = p * 16 + cc;
    const f32x4 v =
        *(const f32x4*)&Xs[((size_t)(b * kC + c0 + c)) * kN + n0 + n4];
    tile[c][n4 + 0] = v[0];
    tile[c][n4 + 1] = v[1];
    tile[c][n4 + 2] = v[2];
    tile[c][n4 + 3] = v[3];
  }
  __syncthreads();
  const int n = t >> 2, c8 = (t & 3) * 8;
  bf16x8 o;
#pragma unroll
  for (int j = 0; j < 8; j++) o[j] = (bf16)tile[c8 + j][n];
  *(bf16x8*)&XT[((size_t)(b * kN + n0 + n)) * kC + c0 + c8] = o;
}

// -------- q/k projections (staged GEMM): OT[b][n][128] = (wqk @ src)^T
__global__ __launch_bounds__(256, 2) void k_projQK(
    const bf16* __restrict__ XTq, const bf16* __restrict__ XTx,
    const bf16* __restrict__ W, bf16* __restrict__ qT, bf16* __restrict__ kT) {
  __shared__ __align__(16) bf16 As[2][128][32];
  __shared__ __align__(16) bf16 Bs[2][128][32];
  const int nb = blockIdx.x, b = blockIdx.y, src = blockIdx.z;
  const bf16* XT = src ? XTx : XTq;
  bf16* OT = src ? kT : qT;
  const int n0 = nb * 128;
  const int t_ = threadIdx.x, w = t_ >> 6, l = t_ & 63, lo4 = l & 15, g = l >> 4;
  const int mh = w >> 1, ch = w & 1;
  const int srow = w * 16 + (l >> 2), sch = l & 3;
  const int spos = sch ^ ((l >> 3) & 3);
  const int rpos = g ^ ((lo4 >> 1) & 3);
  const bf16* gA0 = &XT[((size_t)(b * kN + n0 + srow)) * kC + sch * 8];
  const bf16* gA1 = gA0 + (size_t)64 * kC;
  const bf16* gB0 = &W[(size_t)srow * kC + sch * 8];
  const bf16* gB1 = gB0 + (size_t)64 * kC;
  f32x4 acc[4][4] = {};
  bf16x8 ra0, ra1, rb0, rb1;
  ra0 = *(const bf16x8*)&gA0[0];
  ra1 = *(const bf16x8*)&gA1[0];
  rb0 = *(const bf16x8*)&gB0[0];
  rb1 = *(const bf16x8*)&gB1[0];
  *(bf16x8*)&As[0][srow][spos * 8] = ra0;
  *(bf16x8*)&As[0][srow + 64][spos * 8] = ra1;
  *(bf16x8*)&Bs[0][srow][spos * 8] = rb0;
  *(bf16x8*)&Bs[0][srow + 64][spos * 8] = rb1;
  __syncthreads();
  for (int tt = 0; tt < 16; tt++) {
    const int buf = tt & 1;
    if (tt < 15) {
      const int k0 = (tt + 1) * 32;
      ra0 = *(const bf16x8*)&gA0[k0];
      ra1 = *(const bf16x8*)&gA1[k0];
      rb0 = *(const bf16x8*)&gB0[k0];
      rb1 = *(const bf16x8*)&gB1[k0];
    }
    bf16x8 af[4], bfr[4];
#pragma unroll
    for (int nf = 0; nf < 4; nf++)
      af[nf] = *(const bf16x8*)&As[buf][mh * 64 + nf * 16 + lo4][rpos * 8];
#pragma unroll
    for (int cf = 0; cf < 4; cf++)
      bfr[cf] = *(const bf16x8*)&Bs[buf][ch * 64 + cf * 16 + lo4][rpos * 8];
#pragma unroll
    for (int nf = 0; nf < 4; nf++)
#pragma unroll
      for (int cf = 0; cf < 4; cf++)
        acc[nf][cf] = MFMA16(af[nf], bfr[cf], acc[nf][cf]);
    if (tt < 15) {
      *(bf16x8*)&As[buf ^ 1][srow][spos * 8] = ra0;
      *(bf16x8*)&As[buf ^ 1][srow + 64][spos * 8] = ra1;
      *(bf16x8*)&Bs[buf ^ 1][srow][spos * 8] = rb0;
      *(bf16x8*)&Bs[buf ^ 1][srow + 64][spos * 8] = rb1;
    }
    __syncthreads();
  }
  bf16* bncw = ((bf16*)As) + w * 16 * 72;
#pragma unroll
  for (int nf = 0; nf < 4; nf++) {
    const int nbase = n0 + mh * 64 + nf * 16;
#pragma unroll
    for (int cf = 0; cf < 4; cf++)
#pragma unroll
      for (int r = 0; r < 4; r++)
        bncw[(4 * g + r) * 72 + cf * 16 + lo4] = (bf16)acc[nf][cf][r];
    const int rr = l >> 2, seg = (l & 3) * 16;
    const bf16x8 v0 = *(const bf16x8*)&bncw[rr * 72 + seg];
    const bf16x8 v1 = *(const bf16x8*)&bncw[rr * 72 + seg + 8];
    bf16* orow = &OT[((size_t)(b * kN + nbase + rr)) * kC4 + ch * 64 + seg];
    *(bf16x8*)&orow[0] = v0;
    *(bf16x8*)&orow[8] = v1;
  }
}

// -------- value projection (staged GEMM) -> TILED xv2[b][n>>6][c][n&63]
__global__ __launch_bounds__(256, 2) void k_projV(
    const bf16* __restrict__ XTx, const bf16* __restrict__ Wv,
    const float* __restrict__ bv, bf16* __restrict__ xv2) {
  __shared__ __align__(16) bf16 As[2][128][32];
  __shared__ __align__(16) bf16 Bs[2][128][32];
  const int blk = blockIdx.x;  // 512 = 8b x (16nb x 4cb)
  const int b = blk & 7, tile = blk >> 3;
  const int cb = tile & 3, nb = tile >> 2;
  const int n0 = nb * 128, c0 = cb * 128;
  const int t_ = threadIdx.x, w = t_ >> 6, l = t_ & 63, lo4 = l & 15, g = l >> 4;
  const int mh = w >> 1, ch = w & 1;
  const int srow = w * 16 + (l >> 2), sch = l & 3;
  const int spos = sch ^ ((l >> 3) & 3);
  const int rpos = g ^ ((lo4 >> 1) & 3);
  const bf16* gA0 = &XTx[((size_t)(b * kN + n0 + srow)) * kC + sch * 8];
  const bf16* gA1 = gA0 + (size_t)64 * kC;
  const bf16* gB0 = &Wv[(size_t)(c0 + srow) * kC + sch * 8];
  const bf16* gB1 = gB0 + (size_t)64 * kC;
  f32x4 acc[4][4] = {};
  bf16x8 ra0, ra1, rb0, rb1;
  ra0 = *(const bf16x8*)&gA0[0];
  ra1 = *(const bf16x8*)&gA1[0];
  rb0 = *(const bf16x8*)&gB0[0];
  rb1 = *(const bf16x8*)&gB1[0];
  *(bf16x8*)&As[0][srow][spos * 8] = ra0;
  *(bf16x8*)&As[0][srow + 64][spos * 8] = ra1;
  *(bf16x8*)&Bs[0][srow][spos * 8] = rb0;
  *(bf16x8*)&Bs[0][srow + 64][spos * 8] = rb1;
  __syncthreads();
  for (int tt = 0; tt < 16; tt++) {
    const int buf = tt & 1;
    if (tt < 15) {
      const int k0 = (tt + 1) * 32;
      ra0 = *(const bf16x8*)&gA0[k0];
      ra1 = *(const bf16x8*)&gA1[k0];
      rb0 = *(const bf16x8*)&gB0[k0];
      rb1 = *(const bf16x8*)&gB1[k0];
    }
    bf16x8 af[4], bfr[4];
#pragma unroll
    for (int nf = 0; nf < 4; nf++)
      af[nf] = *(const bf16x8*)&As[buf][mh * 64 + nf * 16 + lo4][rpos * 8];
#pragma unroll
    for (int cf = 0; cf < 4; cf++)
      bfr[cf] = *(const bf16x8*)&Bs[buf][ch * 64 + cf * 16 + lo4][rpos * 8];
#pragma unroll
    for (int nf = 0; nf < 4; nf++)
#pragma unroll
      for (int cf = 0; cf < 4; cf++)
        acc[nf][cf] = MFMA16(af[nf], bfr[cf], acc[nf][cf]);
    if (tt < 15) {
      *(bf16x8*)&As[buf ^ 1][srow][spos * 8] = ra0;
      *(bf16x8*)&As[buf ^ 1][srow + 64][spos * 8] = ra1;
      *(bf16x8*)&Bs[buf ^ 1][srow][spos * 8] = rb0;
      *(bf16x8*)&Bs[buf ^ 1][srow + 64][spos * 8] = rb1;
    }
    __syncthreads();
  }
#pragma unroll
  for (int cf = 0; cf < 4; cf++) {
    const int c = c0 + ch * 64 + cf * 16 + lo4;
    const float bvv = bv[c];
#pragma unroll
    for (int nf = 0; nf < 4; nf++) {
      const int nbase = n0 + mh * 64 + nf * 16 + g * 4;
      bf16x4 o;
#pragma unroll
      for (int r = 0; r < 4; r++) o[r] = (bf16)(acc[nf][cf][r] + bvv);
      *(bf16x4*)&xv2[(((size_t)b * 32 + (nbase >> 6)) * kC + c) * 64 +
                     (nbase & 63)] = o;
    }
  }
}

// ---------------- pass 1: U^T[m][n] exp-factors -> fp8 UT8; partial S[n].
__global__ __launch_bounds__(256) void k_sum(
    const bf16* __restrict__ qT, const bf16* __restrict__ kT,
    const int* __restrict__ mask, const float* __restrict__ cnt,
    unsigned char* __restrict__ UT8, float* __restrict__ Ssum) {
  __shared__ __align__(16) bf16 kts[2][64][128];
  __shared__ __align__(16) unsigned Ubuf[64][16];
  __shared__ int mss[2][64];
  const int blk = blockIdx.x;
  const int b = blk & 7, nb = (blk >> 3) & 31, mh2 = blk >> 8;
  const int m00 = mh2 * 1024;
  const int t_ = threadIdx.x, w = t_ >> 6, l = t_ & 63, lo4 = l & 15, g = l >> 4;
  const float invd = 1.0f / (cnt[b] + 1e-9f);
  const int n0 = nb * 64;
  bf16x8 aq[4];
#pragma unroll
  for (int ks = 0; ks < 4; ks++)
    aq[ks] = *(const bf16x8*)&qT[((size_t)(b * kN + n0 + w * 16 + lo4)) * kC4 +
                                 ks * 32 + g * 8];
  const int nq = n0 + w * 16 + g * 4;
  const int4 mi = *(const int4*)&mask[b * kN + nq];
  const int mn4[4] = {mi.x, mi.y, mi.z, mi.w};
  float rs4[4] = {0.0f, 0.0f, 0.0f, 0.0f};
  bf16x8 rg[4];
#pragma unroll
  for (int i = 0; i < 4; i++) {
    const int row = w * 16 + i * 4 + g;
    const int q = (l & 15) ^ (row & 7);
    rg[i] = *(const bf16x8*)&kT[((size_t)(b * kN + m00 + row)) * kC4 + q * 8];
  }
#pragma unroll
  for (int i = 0; i < 4; i++) {
    const int row = w * 16 + i * 4 + g;
    *(bf16x8*)&kts[0][row][(l & 15) * 8] = rg[i];
  }
  if (t_ < 16)
    *(int4*)&mss[0][t_ * 4] = *(const int4*)&mask[b * kN + m00 + t_ * 4];
  __syncthreads();
  for (int tt = 0; tt < 16; tt++) {
    const int buf = tt & 1;
    if (tt < 15) {
      const int m0 = m00 + (tt + 1) * 64;
#pragma unroll
      for (int i = 0; i < 4; i++) {
        const int row = w * 16 + i * 4 + g;
        const int q = (l & 15) ^ (row & 7);
        rg[i] = *(const bf16x8*)&kT[((size_t)(b * kN + m0 + row)) * kC4 + q * 8];
      }
    }
#pragma unroll
    for (int mf = 0; mf < 4; mf++) {
      f32x4 e = {};
#pragma unroll
      for (int ks = 0; ks < 4; ks++) {
        const bf16x8 bk =
            *(const bf16x8*)&kts[buf][mf * 16 + lo4]
                                 [((ks * 4 + g) ^ (lo4 & 7)) * 8];
        e = MFMA16(aq[ks], bk, e);
      }
      const int mmv = mss[buf][mf * 16 + lo4];
      float u[4];
#pragma unroll
      for (int r = 0; r < 4; r++) {
        u[r] = mmv ? (mn4[r] ? __expf(e[r] * invd) : 1.0f) : 0.0f;
        rs4[r] += u[r];
      }
      Ubuf[mf * 16 + lo4][(w * 4 + g) ^ lo4] =
          pack4_fp8(u[0], u[1], u[2], u[3]);
    }
    __syncthreads();
    if (tt < 15) {
#pragma unroll
      for (int i = 0; i < 4; i++) {
        const int row = w * 16 + i * 4 + g;
        *(bf16x8*)&kts[buf ^ 1][row][(l & 15) * 8] = rg[i];
      }
      if (t_ < 16)
        *(int4*)&mss[buf ^ 1][t_ * 4] =
            *(const int4*)&mask[b * kN + m00 + (tt + 1) * 64 + t_ * 4];
    }
    {
      const int row = t_ >> 2, q = t_ & 3;
      int4 pkt;
      pkt.x = (int)Ubuf[row][(q * 4 + 0) ^ (row & 15)];
      pkt.y = (int)Ubuf[row][(q * 4 + 1) ^ (row & 15)];
      pkt.z = (int)Ubuf[row][(q * 4 + 2) ^ (row & 15)];
      pkt.w = (int)Ubuf[row][(q * 4 + 3) ^ (row & 15)];
      *(int4*)&UT8[((size_t)(b * kN + m00 + tt * 64 + row)) * kN + n0 +
                   q * 16] = pkt;
    }
    __syncthreads();
  }
#pragma unroll
  for (int r = 0; r < 4; r++) {
#pragma unroll
    for (int off = 1; off < 16; off <<= 1) rs4[r] += __shfl_xor(rs4[r], off);
  }
  if (lo4 == 0) {
#pragma unroll
    for (int r = 0; r < 4; r++) atomicAdd(&Ssum[b * kN + nq + r], rs4[r]);
  }
}

// ---------------- xv2 (bf16 tiled) * (1/Ssum[n]) -> xv8 (fp8 tiled)
__global__ __launch_bounds__(256) void k_scale(const bf16* __restrict__ xv2,
                                               const float* __restrict__ Ssum,
                                               unsigned* __restrict__ xv8) {
  const int blk = blockIdx.x;  // 1024 = 8b x 128 parts
  const int b = blk & 7, part = blk >> 3;
  const size_t base = (size_t)b * (32 * kC * 64);
  for (int it = 0; it < 4; it++) {
    const int chunk = part * 1024 + it * 256 + threadIdx.x;
    const size_t e = (size_t)chunk * 8;
    const int n = ((int)(e >> 15)) * 64 + ((int)e & 63);
    const bf16x8 v = *(const bf16x8*)&xv2[base + e];
    const f32x4 ss0 = *(const f32x4*)&Ssum[b * kN + n];
    const f32x4 ss1 = *(const f32x4*)&Ssum[b * kN + n + 4];
    f32x4 s0, s1;
#pragma unroll
    for (int j = 0; j < 4; j++) {
      s0[j] = 1.0f / ss0[j];
      s1[j] = 1.0f / ss1[j];
    }
    uint2 o;
    o.x = pack4_fp8((float)v[0] * s0[0], (float)v[1] * s0[1],
                    (float)v[2] * s0[2], (float)v[3] * s0[3]);
    o.y = pack4_fp8((float)v[4] * s1[0], (float)v[5] * s1[1],
                    (float)v[6] * s1[2], (float)v[7] * s1[3]);
    *(uint2*)&xv8[(base + e) >> 2] = o;
  }
}

// -------- pass 2 (fp8, BK=128): x_r^T[m][c] = sum_n UT8[m][n]*xv8[c][n]
// 128m x 128c tile, 16 iters x 64 MFMA, depth-2 even/odd reg pipeline.
// LDS rows 128B: full XOR swizzle v = u ^ (row&15) on 8B units.
__global__ __launch_bounds__(256, 2) void k_attn2(
    const unsigned char* __restrict__ UT8,
    const unsigned char* __restrict__ xv8, const float* __restrict__ x,
    bf16* __restrict__ hT) {
  __shared__ __align__(16) unsigned char As[2][128][128];
  __shared__ __align__(16) unsigned char Bs[2][128][128];
  const int blk = blockIdx.x;  // 512 = 8b x (16mb x 4cb)
  const int b = blk & 7, tile = blk >> 3;
  const int cb = tile & 3, mb = tile >> 2;
  const int m0 = mb * 128, c0 = cb * 128;
  const int t_ = threadIdx.x, w = t_ >> 6, l = t_ & 63, lo4 = l & 15, g = l >> 4;
  const int mh = w >> 1, ch = w & 1;
  const int srow = t_ >> 1, psl = t_ & 1;  // 64B half per thread
  const int swk = srow & 15;               // write swizzle key
  const unsigned char* gA = &UT8[((size_t)(b * kN + m0 + srow)) * kN + psl * 64];
  const unsigned char* gB =
      &xv8[(((size_t)b * 32 + psl) * kC + c0 + srow) * 64];
  f32x4 acc[4][4] = {};
  ulonglong2 eA[4], eB[4], oA[4], oB[4];
#define LOADSET(RA, RB, T)                                                     \
  {                                                                            \
    _Pragma("unroll") for (int q = 0; q < 4; q++) {                            \
      RA[q] = *(const ulonglong2*)&gA[(size_t)(T)*128 + q * 16];               \
      RB[q] = *(const ulonglong2*)&gB[(size_t)(T)*65536 + q * 16];             \
    }                                                                          \
  }
#define STORE_TILE(BUF, RA, RB)                                                \
  {                                                                            \
    _Pragma("unroll") for (int j = 0; j < 8; j++) {                            \
      const int v = (psl * 8 + j) ^ swk;                                       \
      const u64 va = (j & 1) ? RA[j >> 1].y : RA[j >> 1].x;                    \
      const u64 vb = (j & 1) ? RB[j >> 1].y : RB[j >> 1].x;                    \
      *(u64*)&As[BUF][srow][v * 8] = va;                                       \
      *(u64*)&Bs[BUF][srow][v * 8] = vb;                                       \
    }                                                                          \
  }
#define FRAGS_MFMA(BUF)                                                        \
  {                                                                            \
    _Pragma("unroll") for (int ks = 0; ks < 4; ks++) {                         \
      long af[4], bfr[4];                                                      \
      _Pragma("unroll") for (int mf = 0; mf < 4; mf++) af[mf] =                \
          *(const long*)&As[BUF][mh * 64 + mf * 16 + lo4]                      \
                            [((ks * 4 + g) ^ lo4) * 8];                        \
      _Pragma("unroll") for (int cf = 0; cf < 4; cf++) bfr[cf] =               \
          *(const long*)&Bs[BUF][ch * 64 + cf * 16 + lo4]                      \
                            [((ks * 4 + g) ^ lo4) * 8];                        \
      _Pragma("unroll") for (int mf = 0; mf < 4; mf++)                         \
          _Pragma("unroll") for (int cf = 0; cf < 4; cf++) acc[mf][cf] =       \
              MFMA8(af[mf], bfr[cf], acc[mf][cf]);                             \
    }                                                                          \
  }
  // prologue: iter0 -> LDS[0]; iter1 pending in regs
  LOADSET(eA, eB, 0);
  STORE_TILE(0, eA, eB);
  LOADSET(oA, oB, 1);
  __syncthreads();
  for (int tt2 = 0; tt2 < 16; tt2 += 2) {
    if (tt2 + 2 < 16) LOADSET(eA, eB, tt2 + 2);
    FRAGS_MFMA(0);
    STORE_TILE(1, oA, oB);
    __syncthreads();
    if (tt2 + 3 < 16) LOADSET(oA, oB, tt2 + 3);
    FRAGS_MFMA(1);
    if (tt2 + 2 < 16) STORE_TILE(0, eA, eB);
    __syncthreads();
  }
#undef FRAGS_MFMA
#undef STORE_TILE
#undef LOADSET
  // epilogue: h = x - x_r; per-wave LDS transpose (alias As) -> hT[m][c]
  bf16* bncw = ((bf16*)As) + w * 16 * 72;
#pragma unroll
  for (int mf = 0; mf < 4; mf++) {
    const int mbase = m0 + mh * 64 + mf * 16;
    float hh[4][4];
#pragma unroll
    for (int cf = 0; cf < 4; cf++) {
      const int c = c0 + ch * 64 + cf * 16 + lo4;
      const f32x4 xval =
          *(const f32x4*)&x[((size_t)(b * kC + c)) * kN + mbase + g * 4];
#pragma unroll
      for (int r = 0; r < 4; r++) hh[cf][r] = xval[r] - acc[mf][cf][r];
    }
#pragma unroll
    for (int cf = 0; cf < 4; cf++)
#pragma unroll
      for (int r = 0; r < 4; r++)
        bncw[(4 * g + r) * 72 + cf * 16 + lo4] = (bf16)hh[cf][r];
    {
      const int rr = l >> 2, seg = (l & 3) * 16;
      const bf16x8 v0 = *(const bf16x8*)&bncw[rr * 72 + seg];
      const bf16x8 v1 = *(const bf16x8*)&bncw[rr * 72 + seg + 8];
      bf16* orow =
          &hT[((size_t)(b * kN + mbase + rr)) * kC + c0 + ch * 64 + seg];
      *(bf16x8*)&orow[0] = v0;
      *(bf16x8*)&orow[8] = v1;
    }
  }
}

// -------- final: D[n][c] = hT[n][k] wt[c][k]; BN+ReLU+residual
__global__ __launch_bounds__(256, 2) void k_final(
    const bf16* __restrict__ hT, const bf16* __restrict__ wt_bf,
    const float* __restrict__ x, const float* __restrict__ bt,
    const float* __restrict__ beta, const float* __restrict__ rmean,
    const float* __restrict__ invg, float* __restrict__ out) {
  __shared__ __align__(16) bf16 As[2][128][32];
  __shared__ __align__(16) bf16 Bs[2][128][32];
  const int blk = blockIdx.x;  // 512 = 8b x (16nb x 4cb)
  const int b = blk & 7, tile = blk >> 3;
  const int cb = tile & 3, nb = tile >> 2;
  const int n0 = nb * 128, c0 = cb * 128;
  const int t_ = threadIdx.x, w = t_ >> 6, l = t_ & 63, lo4 = l & 15, g = l >> 4;
  const int mh = w >> 1, ch = w & 1;
  const int srow = w * 16 + (l >> 2), sch = l & 3;
  const int spos = sch ^ ((l >> 3) & 3);
  const int rpos = g ^ ((lo4 >> 1) & 3);
  const bf16* gA0 = &hT[((size_t)(b * kN + n0 + srow)) * kC + sch * 8];
  const bf16* gA1 = gA0 + (size_t)64 * kC;
  const bf16* gB0 = &wt_bf[(size_t)(c0 + srow) * kC + sch * 8];
  const bf16* gB1 = gB0 + (size_t)64 * kC;
  f32x4 acc[4][4] = {};
  bf16x8 ra0, ra1, rb0, rb1;
  ra0 = *(const bf16x8*)&gA0[0];
  ra1 = *(const bf16x8*)&gA1[0];
  rb0 = *(const bf16x8*)&gB0[0];
  rb1 = *(const bf16x8*)&gB1[0];
  *(bf16x8*)&As[0][srow][spos * 8] = ra0;
  *(bf16x8*)&As[0][srow + 64][spos * 8] = ra1;
  *(bf16x8*)&Bs[0][srow][spos * 8] = rb0;
  *(bf16x8*)&Bs[0][srow + 64][spos * 8] = rb1;
  __syncthreads();
  for (int tt = 0; tt < 16; tt++) {
    const int buf = tt & 1;
    if (tt < 15) {
      const int k0 = (tt + 1) * 32;
      ra0 = *(const bf16x8*)&gA0[k0];
      ra1 = *(const bf16x8*)&gA1[k0];
      rb0 = *(const bf16x8*)&gB0[k0];
      rb1 = *(const bf16x8*)&gB1[k0];
    }
    bf16x8 af[4], bfr[4];
#pragma unroll
    for (int nf = 0; nf < 4; nf++)
      af[nf] = *(const bf16x8*)&As[buf][mh * 64 + nf * 16 + lo4][rpos * 8];
#pragma unroll
    for (int cf = 0; cf < 4; cf++)
      bfr[cf] = *(const bf16x8*)&Bs[buf][ch * 64 + cf * 16 + lo4][rpos * 8];
#pragma unroll
    for (int nf = 0; nf < 4; nf++)
#pragma unroll
      for (int cf = 0; cf < 4; cf++)
        acc[nf][cf] = MFMA16(af[nf], bfr[cf], acc[nf][cf]);
    if (tt < 15) {
      *(bf16x8*)&As[buf ^ 1][srow][spos * 8] = ra0;
      *(bf16x8*)&As[buf ^ 1][srow + 64][spos * 8] = ra1;
      *(bf16x8*)&Bs[buf ^ 1][srow][spos * 8] = rb0;
      *(bf16x8*)&Bs[buf ^ 1][srow + 64][spos * 8] = rb1;
    }
    __syncthreads();
  }
#pragma unroll
  for (int cf = 0; cf < 4; cf++) {
    const int c = c0 + ch * 64 + cf * 16 + lo4;
    const float btv = bt[c], rmv = rmean[c], igv = invg[c], bev = beta[c];
#pragma unroll
    for (int nf = 0; nf < 4; nf++) {
      const int nbase = n0 + mh * 64 + nf * 16 + g * 4;
      const size_t base = ((size_t)(b * kC + c)) * kN + nbase;
      const f32x4 xval = *(const f32x4*)&x[base];
      f32x4 o;
#pragma unroll
      for (int r = 0; r < 4; r++) {
        float v = (acc[nf][cf][r] + btv - rmv) * igv + bev;
        v = fmaxf(v, 0.0f);
        o[r] = xval[r] + v;
      }
      *(f32x4*)&out[base] = o;
    }
  }
}

extern "C" void kernel_launch(void* const* d_in, const int* in_sizes, int n_in,
                              void* d_out, int out_size, void* d_ws,
                              size_t ws_size, hipStream_t stream) {
  const float* x = (const float*)d_in[0];
  const float* query = (const float*)d_in[1];
  const int* mask = (const int*)d_in[2];
  const float* wqk = (const float*)d_in[3];
  const float* wv = (const float*)d_in[4];
  const float* bv = (const float*)d_in[5];
  const float* wt = (const float*)d_in[6];
  const float* bt = (const float*)d_in[7];
  const float* gamma = (const float*)d_in[8];
  const float* beta = (const float*)d_in[9];
  const float* rmean = (const float*)d_in[10];
  const float* rvar = (const float*)d_in[11];
  float* out = (float*)d_out;
  char* wsb = (char*)d_ws;

  const size_t MB = 1024 * 1024;
  unsigned char* UT8 = (unsigned char*)wsb;     // 32 MB [b][m][n] fp8
  bf16* trbufQ = (bf16*)wsb;                    // 16 MB (UT8 dead zone)
  bf16* trbufX = (bf16*)(wsb + 16 * MB);        // 16 MB (UT8 dead zone)
  bf16* xv2 = (bf16*)(wsb + 32 * MB);           // 16 MB bf16 tiled
  unsigned* xv8 = (unsigned*)(wsb + 48 * MB);   // 8 MB fp8 tiled
  bf16* hT = (bf16*)(wsb + 56 * MB);            // 8 MB [b][n][c]
  bf16* qT = (bf16*)(wsb + 64 * MB);            // 4 MB
  bf16* kT = (bf16*)(wsb + 68 * MB);            // 4 MB
  bf16* wqk_bf = (bf16*)(wsb + 72 * MB);        // 128 KB
  bf16* wv_bf = wqk_bf + 65536;                 // 512 KB
  bf16* wt_bf = wv_bf + 262144;                 // 512 KB
  float* invg = (float*)(wt_bf + 262144);       // 2 KB
  float* Ssum = invg + 512;                     // 64 KB
  float* cnt = Ssum + kB * kN;                  // 32 B

  k_prep<<<136, 256, 0, stream>>>(mask, wqk, wv, wt, gamma, rvar, cnt, wqk_bf,
                                  wv_bf, wt_bf, invg, Ssum);
  k_tr2<<<dim3(kN / 64, kC / 32, 16), 256, 0, stream>>>(query, x, trbufQ,
                                                        trbufX);
  k_projQK<<<dim3(16, kB, 2), 256, 0, stream>>>(trbufQ, trbufX, wqk_bf, qT,
                                                kT);
  k_projV<<<512, 256, 0, stream>>>(trbufX, wv_bf, bv, xv2);
  k_sum<<<512, 256, 0, stream>>>(qT, kT, mask, cnt, UT8, Ssum);
  k_scale<<<1024, 256, 0, stream>>>(xv2, Ssum, xv8);
  k_attn2<<<512, 256, 0, stream>>>(UT8, (const unsigned char*)xv8, x, hT);
  k_final<<<512, 256, 0, stream>>>(hT, wt_bf, x, bt, beta, rmean, invg, out);
}

// Round 19
// 133.900 us; speedup vs baseline: 1.3438x; 1.1001x over previous
//
#include <hip/hip_runtime.h>
#include <math.h>

typedef __bf16 bf16;
typedef bf16 bf16x8 __attribute__((ext_vector_type(8)));
typedef bf16 bf16x4 __attribute__((ext_vector_type(4)));
typedef float f32x4 __attribute__((ext_vector_type(4)));
typedef unsigned long long u64;

constexpr int kB = 8, kC = 512, kC4 = 128, kN = 2048;

#define MFMA16(a, b, c) __builtin_amdgcn_mfma_f32_16x16x32_bf16(a, b, c, 0, 0, 0)
#define MFMA8(a, b, c) \
  __builtin_amdgcn_mfma_f32_16x16x32_fp8_fp8(a, b, c, 0, 0, 0)

__device__ __forceinline__ unsigned pack4_fp8(float a, float b, float c,
                                              float d) {
  unsigned v = 0;
  v = __builtin_amdgcn_cvt_pk_fp8_f32(a, b, v, false);
  v = __builtin_amdgcn_cvt_pk_fp8_f32(c, d, v, true);
  return v;
}

// ---------------------------------------------------------------- prep
__global__ __launch_bounds__(256) void k_prep(
    const int* __restrict__ mask, const float* __restrict__ wqk,
    const float* __restrict__ wv, const float* __restrict__ wt,
    const float* __restrict__ gamma, const float* __restrict__ rvar,
    float* __restrict__ cnt, bf16* __restrict__ wqk_bf,
    bf16* __restrict__ wv_bf, bf16* __restrict__ wt_bf,
    float* __restrict__ invg, float* __restrict__ Ssum) {
  const int t = threadIdx.x;
  if (blockIdx.x < 8) {
    const int b = blockIdx.x;
    int s = 0;
    for (int i = t; i < kN; i += 256) s += mask[b * kN + i];
    __shared__ int red[256];
    red[t] = s;
    __syncthreads();
    for (int off = 128; off > 0; off >>= 1) {
      if (t < off) red[t] += red[t + off];
      __syncthreads();
    }
    if (t == 0) cnt[b] = (float)red[0];
    return;
  }
  const int total = 65536 + 262144 + 262144 + 512 + 16384;
  for (int i = (blockIdx.x - 8) * 256 + t; i < total; i += 128 * 256) {
    if (i < 65536) {
      wqk_bf[i] = (bf16)wqk[i];
    } else if (i < 327680) {
      wv_bf[i - 65536] = (bf16)wv[i - 65536];
    } else if (i < 589824) {
      wt_bf[i - 327680] = (bf16)wt[i - 327680];
    } else if (i < 590336) {
      const int j = i - 589824;
      invg[j] = gamma[j] * rsqrtf(rvar[j] + 1e-5f);
    } else {
      Ssum[i - 590336] = 0.0f;
    }
  }
}

// ---------------- transpose+convert both inputs: [C][N] f32 -> [N][C] bf16
__global__ __launch_bounds__(256) void k_tr2(const float* __restrict__ Q,
                                             const float* __restrict__ X,
                                             bf16* __restrict__ XTq,
                                             bf16* __restrict__ XTx) {
  __shared__ float tile[32][69];
  const int z = blockIdx.z, b = z & 7;
  const float* Xs = (z < 8) ? Q : X;
  bf16* XT = (z < 8) ? XTq : XTx;
  const int c0 = blockIdx.y * 32, n0 = blockIdx.x * 64;
  const int t = threadIdx.x;
  const int cc = t >> 4, n4 = (t & 15) * 4;
#pragma unroll
  for (int p = 0; p < 2; p++) {
    const int c = p * 16 + cc;
    const f32x4 v =
        *(const f32x4*)&Xs[((size_t)(b * kC + c0 + c)) * kN + n0 + n4];
    tile[c][n4 + 0] = v[0];
    tile[c][n4 + 1] = v[1];
    tile[c][n4 + 2] = v[2];
    tile[c][n4 + 3] = v[3];
  }
  __syncthreads();
  const int n = t >> 2, c8 = (t & 3) * 8;
  bf16x8 o;
#pragma unroll
  for (int j = 0; j < 8; j++) o[j] = (bf16)tile[c8 + j][n];
  *(bf16x8*)&XT[((size_t)(b * kN + n0 + n)) * kC + c0 + c8] = o;
}

// -------- q/k projections (staged GEMM): OT8[b][n][128] fp8 = (wqk @ src)^T
__global__ __launch_bounds__(256, 2) void k_projQK(
    const bf16* __restrict__ XTq, const bf16* __restrict__ XTx,
    const bf16* __restrict__ W, unsigned char* __restrict__ qT8,
    unsigned char* __restrict__ kT8) {
  __shared__ __align__(16) bf16 As[2][128][32];
  __shared__ __align__(16) bf16 Bs[2][128][32];
  const int nb = blockIdx.x, b = blockIdx.y, src = blockIdx.z;
  const bf16* XT = src ? XTx : XTq;
  unsigned char* OT8 = src ? kT8 : qT8;
  const int n0 = nb * 128;
  const int t_ = threadIdx.x, w = t_ >> 6, l = t_ & 63, lo4 = l & 15, g = l >> 4;
  const int mh = w >> 1, ch = w & 1;
  const int srow = w * 16 + (l >> 2), sch = l & 3;
  const int spos = sch ^ ((l >> 3) & 3);
  const int rpos = g ^ ((lo4 >> 1) & 3);
  const bf16* gA0 = &XT[((size_t)(b * kN + n0 + srow)) * kC + sch * 8];
  const bf16* gA1 = gA0 + (size_t)64 * kC;
  const bf16* gB0 = &W[(size_t)srow * kC + sch * 8];
  const bf16* gB1 = gB0 + (size_t)64 * kC;
  f32x4 acc[4][4] = {};
  bf16x8 ra0, ra1, rb0, rb1;
  ra0 = *(const bf16x8*)&gA0[0];
  ra1 = *(const bf16x8*)&gA1[0];
  rb0 = *(const bf16x8*)&gB0[0];
  rb1 = *(const bf16x8*)&gB1[0];
  *(bf16x8*)&As[0][srow][spos * 8] = ra0;
  *(bf16x8*)&As[0][srow + 64][spos * 8] = ra1;
  *(bf16x8*)&Bs[0][srow][spos * 8] = rb0;
  *(bf16x8*)&Bs[0][srow + 64][spos * 8] = rb1;
  __syncthreads();
  for (int tt = 0; tt < 16; tt++) {
    const int buf = tt & 1;
    if (tt < 15) {
      const int k0 = (tt + 1) * 32;
      ra0 = *(const bf16x8*)&gA0[k0];
      ra1 = *(const bf16x8*)&gA1[k0];
      rb0 = *(const bf16x8*)&gB0[k0];
      rb1 = *(const bf16x8*)&gB1[k0];
    }
    bf16x8 af[4], bfr[4];
#pragma unroll
    for (int nf = 0; nf < 4; nf++)
      af[nf] = *(const bf16x8*)&As[buf][mh * 64 + nf * 16 + lo4][rpos * 8];
#pragma unroll
    for (int cf = 0; cf < 4; cf++)
      bfr[cf] = *(const bf16x8*)&Bs[buf][ch * 64 + cf * 16 + lo4][rpos * 8];
#pragma unroll
    for (int nf = 0; nf < 4; nf++)
#pragma unroll
      for (int cf = 0; cf < 4; cf++)
        acc[nf][cf] = MFMA16(af[nf], bfr[cf], acc[nf][cf]);
    if (tt < 15) {
      *(bf16x8*)&As[buf ^ 1][srow][spos * 8] = ra0;
      *(bf16x8*)&As[buf ^ 1][srow + 64][spos * 8] = ra1;
      *(bf16x8*)&Bs[buf ^ 1][srow][spos * 8] = rb0;
      *(bf16x8*)&Bs[buf ^ 1][srow + 64][spos * 8] = rb1;
    }
    __syncthreads();
  }
  // epilogue: per-wave LDS transpose -> fp8 pack -> OT8[n][d]
  bf16* bncw = ((bf16*)As) + w * 16 * 72;
#pragma unroll
  for (int nf = 0; nf < 4; nf++) {
    const int nbase = n0 + mh * 64 + nf * 16;
#pragma unroll
    for (int cf = 0; cf < 4; cf++)
#pragma unroll
      for (int r = 0; r < 4; r++)
        bncw[(4 * g + r) * 72 + cf * 16 + lo4] = (bf16)acc[nf][cf][r];
    const int rr = l >> 2, seg = (l & 3) * 16;
    const bf16x8 v0 = *(const bf16x8*)&bncw[rr * 72 + seg];
    const bf16x8 v1 = *(const bf16x8*)&bncw[rr * 72 + seg + 8];
    int4 o;
    o.x = (int)pack4_fp8((float)v0[0], (float)v0[1], (float)v0[2],
                         (float)v0[3]);
    o.y = (int)pack4_fp8((float)v0[4], (float)v0[5], (float)v0[6],
                         (float)v0[7]);
    o.z = (int)pack4_fp8((float)v1[0], (float)v1[1], (float)v1[2],
                         (float)v1[3]);
    o.w = (int)pack4_fp8((float)v1[4], (float)v1[5], (float)v1[6],
                         (float)v1[7]);
    *(int4*)&OT8[((size_t)(b * kN + nbase + rr)) * kC4 + ch * 64 + seg] = o;
  }
}

// ---------------- pass 1 (fp8 energy): UT8[m][n] = exp-factor; partial S[n]
__global__ __launch_bounds__(256) void k_sum(
    const unsigned char* __restrict__ qT8, const unsigned char* __restrict__ kT8,
    const int* __restrict__ mask, const float* __restrict__ cnt,
    unsigned char* __restrict__ UT8, float* __restrict__ Ssum) {
  __shared__ __align__(16) unsigned char kts[2][64][128];
  __shared__ __align__(16) unsigned Ubuf[64][16];
  __shared__ int mss[2][64];
  const int blk = blockIdx.x;
  const int b = blk & 7, nb = (blk >> 3) & 31, mh2 = blk >> 8;
  const int m00 = mh2 * 1024;
  const int t_ = threadIdx.x, w = t_ >> 6, l = t_ & 63, lo4 = l & 15, g = l >> 4;
  const float invd = 1.0f / (cnt[b] + 1e-9f);
  const int n0 = nb * 64;
  u64 aq[4];
#pragma unroll
  for (int ks = 0; ks < 4; ks++)
    aq[ks] = *(const u64*)&qT8[((size_t)(b * kN + n0 + w * 16 + lo4)) * kC4 +
                               ks * 32 + g * 8];
  const int nq = n0 + w * 16 + g * 4;
  const int4 mi = *(const int4*)&mask[b * kN + nq];
  const int mn4[4] = {mi.x, mi.y, mi.z, mi.w};
  float rs4[4] = {0.0f, 0.0f, 0.0f, 0.0f};
  const int srow = t_ >> 2, sq = t_ & 3;
  const int swk = srow & 15;
  u64 rg[4];
#pragma unroll
  for (int j = 0; j < 4; j++)
    rg[j] = *(const u64*)&kT8[((size_t)(b * kN + m00 + srow)) * kC4 + sq * 32 +
                              j * 8];
#pragma unroll
  for (int j = 0; j < 4; j++)
    *(u64*)&kts[0][srow][((sq * 4 + j) ^ swk) * 8] = rg[j];
  if (t_ < 16)
    *(int4*)&mss[0][t_ * 4] = *(const int4*)&mask[b * kN + m00 + t_ * 4];
  __syncthreads();
  for (int tt = 0; tt < 16; tt++) {
    const int buf = tt & 1;
    if (tt < 15) {
      const int m0 = m00 + (tt + 1) * 64;
#pragma unroll
      for (int j = 0; j < 4; j++)
        rg[j] = *(const u64*)&kT8[((size_t)(b * kN + m0 + srow)) * kC4 +
                                  sq * 32 + j * 8];
    }
#pragma unroll
    for (int mf = 0; mf < 4; mf++) {
      f32x4 e = {};
#pragma unroll
      for (int ks = 0; ks < 4; ks++) {
        const long bk =
            *(const long*)&kts[buf][mf * 16 + lo4][((ks * 4 + g) ^ lo4) * 8];
        e = MFMA8((long)aq[ks], bk, e);
      }
      const int mmv = mss[buf][mf * 16 + lo4];
      float u[4];
#pragma unroll
      for (int r = 0; r < 4; r++) {
        u[r] = mmv ? (mn4[r] ? __expf(e[r] * invd) : 1.0f) : 0.0f;
        rs4[r] += u[r];
      }
      Ubuf[mf * 16 + lo4][(w * 4 + g) ^ lo4] =
          pack4_fp8(u[0], u[1], u[2], u[3]);
    }
    __syncthreads();
    if (tt < 15) {
#pragma unroll
      for (int j = 0; j < 4; j++)
        *(u64*)&kts[buf ^ 1][srow][((sq * 4 + j) ^ swk) * 8] = rg[j];
      if (t_ < 16)
        *(int4*)&mss[buf ^ 1][t_ * 4] =
            *(const int4*)&mask[b * kN + m00 + (tt + 1) * 64 + t_ * 4];
    }
    {
      const int row = t_ >> 2, q = t_ & 3;
      int4 pkt;
      pkt.x = (int)Ubuf[row][(q * 4 + 0) ^ (row & 15)];
      pkt.y = (int)Ubuf[row][(q * 4 + 1) ^ (row & 15)];
      pkt.z = (int)Ubuf[row][(q * 4 + 2) ^ (row & 15)];
      pkt.w = (int)Ubuf[row][(q * 4 + 3) ^ (row & 15)];
      *(int4*)&UT8[((size_t)(b * kN + m00 + tt * 64 + row)) * kN + n0 +
                   q * 16] = pkt;
    }
    __syncthreads();
  }
#pragma unroll
  for (int r = 0; r < 4; r++) {
#pragma unroll
    for (int off = 1; off < 16; off <<= 1) rs4[r] += __shfl_xor(rs4[r], off);
  }
  if (lo4 == 0) {
#pragma unroll
    for (int r = 0; r < 4; r++) atomicAdd(&Ssum[b * kN + nq + r], rs4[r]);
  }
}

// -------- value projection fused with 256/Ssum scaling -> xv8 fp8 tiled
__global__ __launch_bounds__(256, 2) void k_projV(
    const bf16* __restrict__ XTx, const bf16* __restrict__ Wv,
    const float* __restrict__ bv, const float* __restrict__ Ssum,
    unsigned char* __restrict__ xv8) {
  __shared__ __align__(16) bf16 As[2][128][32];
  __shared__ __align__(16) bf16 Bs[2][128][32];
  const int blk = blockIdx.x;  // 512 = 8b x (16nb x 4cb)
  const int b = blk & 7, tile = blk >> 3;
  const int cb = tile & 3, nb = tile >> 2;
  const int n0 = nb * 128, c0 = cb * 128;
  const int t_ = threadIdx.x, w = t_ >> 6, l = t_ & 63, lo4 = l & 15, g = l >> 4;
  const int mh = w >> 1, ch = w & 1;
  const int srow = w * 16 + (l >> 2), sch = l & 3;
  const int spos = sch ^ ((l >> 3) & 3);
  const int rpos = g ^ ((lo4 >> 1) & 3);
  const bf16* gA0 = &XTx[((size_t)(b * kN + n0 + srow)) * kC + sch * 8];
  const bf16* gA1 = gA0 + (size_t)64 * kC;
  const bf16* gB0 = &Wv[(size_t)(c0 + srow) * kC + sch * 8];
  const bf16* gB1 = gB0 + (size_t)64 * kC;
  f32x4 acc[4][4] = {};
  bf16x8 ra0, ra1, rb0, rb1;
  ra0 = *(const bf16x8*)&gA0[0];
  ra1 = *(const bf16x8*)&gA1[0];
  rb0 = *(const bf16x8*)&gB0[0];
  rb1 = *(const bf16x8*)&gB1[0];
  *(bf16x8*)&As[0][srow][spos * 8] = ra0;
  *(bf16x8*)&As[0][srow + 64][spos * 8] = ra1;
  *(bf16x8*)&Bs[0][srow][spos * 8] = rb0;
  *(bf16x8*)&Bs[0][srow + 64][spos * 8] = rb1;
  __syncthreads();
  for (int tt = 0; tt < 16; tt++) {
    const int buf = tt & 1;
    if (tt < 15) {
      const int k0 = (tt + 1) * 32;
      ra0 = *(const bf16x8*)&gA0[k0];
      ra1 = *(const bf16x8*)&gA1[k0];
      rb0 = *(const bf16x8*)&gB0[k0];
      rb1 = *(const bf16x8*)&gB1[k0];
    }
    bf16x8 af[4], bfr[4];
#pragma unroll
    for (int nf = 0; nf < 4; nf++)
      af[nf] = *(const bf16x8*)&As[buf][mh * 64 + nf * 16 + lo4][rpos * 8];
#pragma unroll
    for (int cf = 0; cf < 4; cf++)
      bfr[cf] = *(const bf16x8*)&Bs[buf][ch * 64 + cf * 16 + lo4][rpos * 8];
#pragma unroll
    for (int nf = 0; nf < 4; nf++)
#pragma unroll
      for (int cf = 0; cf < 4; cf++)
        acc[nf][cf] = MFMA16(af[nf], bfr[cf], acc[nf][cf]);
    if (tt < 15) {
      *(bf16x8*)&As[buf ^ 1][srow][spos * 8] = ra0;
      *(bf16x8*)&As[buf ^ 1][srow + 64][spos * 8] = ra1;
      *(bf16x8*)&Bs[buf ^ 1][srow][spos * 8] = rb0;
      *(bf16x8*)&Bs[buf ^ 1][srow + 64][spos * 8] = rb1;
    }
    __syncthreads();
  }
  // epilogue: (acc + bias) * 256/Ssum[n] -> fp8, tiled layout
#pragma unroll
  for (int nf = 0; nf < 4; nf++) {
    const int nbase = n0 + mh * 64 + nf * 16 + g * 4;
    const f32x4 ssv = *(const f32x4*)&Ssum[b * kN + nbase];
    f32x4 s;
#pragma unroll
    for (int r = 0; r < 4; r++) s[r] = 256.0f / ssv[r];
#pragma unroll
    for (int cf = 0; cf < 4; cf++) {
      const int c = c0 + ch * 64 + cf * 16 + lo4;
      const float bvv = bv[c];
      const unsigned o = pack4_fp8((acc[nf][cf][0] + bvv) * s[0],
                                   (acc[nf][cf][1] + bvv) * s[1],
                                   (acc[nf][cf][2] + bvv) * s[2],
                                   (acc[nf][cf][3] + bvv) * s[3]);
      *(unsigned*)&xv8[(((size_t)b * 32 + (nbase >> 6)) * kC + c) * 64 +
                       (nbase & 63)] = o;
    }
  }
}

// -------- pass 2 (fp8, BK=128): x_r = 2^-8 * sum_n UT8[m][n]*xv8[c][n]
__global__ __launch_bounds__(256, 2) void k_attn2(
    const unsigned char* __restrict__ UT8,
    const unsigned char* __restrict__ xv8, const float* __restrict__ x,
    bf16* __restrict__ hT) {
  __shared__ __align__(16) unsigned char As[2][128][128];
  __shared__ __align__(16) unsigned char Bs[2][128][128];
  const int blk = blockIdx.x;  // 512 = 8b x (16mb x 4cb)
  const int b = blk & 7, tile = blk >> 3;
  const int cb = tile & 3, mb = tile >> 2;
  const int m0 = mb * 128, c0 = cb * 128;
  const int t_ = threadIdx.x, w = t_ >> 6, l = t_ & 63, lo4 = l & 15, g = l >> 4;
  const int mh = w >> 1, ch = w & 1;
  const int srow = t_ >> 1, psl = t_ & 1;
  const int swk = srow & 15;
  const unsigned char* gA = &UT8[((size_t)(b * kN + m0 + srow)) * kN + psl * 64];
  const unsigned char* gB =
      &xv8[(((size_t)b * 32 + psl) * kC + c0 + srow) * 64];
  f32x4 acc[4][4] = {};
  ulonglong2 eA[4], eB[4], oA[4], oB[4];
#define LOADSET(RA, RB, T)                                                     \
  {                                                                            \
    _Pragma("unroll") for (int q = 0; q < 4; q++) {                            \
      RA[q] = *(const ulonglong2*)&gA[(size_t)(T)*128 + q * 16];               \
      RB[q] = *(const ulonglong2*)&gB[(size_t)(T)*65536 + q * 16];             \
    }                                                                          \
  }
#define STORE_TILE(BUF, RA, RB)                                                \
  {                                                                            \
    _Pragma("unroll") for (int j = 0; j < 8; j++) {                            \
      const int v = (psl * 8 + j) ^ swk;                                       \
      const u64 va = (j & 1) ? RA[j >> 1].y : RA[j >> 1].x;                    \
      const u64 vb = (j & 1) ? RB[j >> 1].y : RB[j >> 1].x;                    \
      *(u64*)&As[BUF][srow][v * 8] = va;                                       \
      *(u64*)&Bs[BUF][srow][v * 8] = vb;                                       \
    }                                                                          \
  }
#define FRAGS_MFMA(BUF)                                                        \
  {                                                                            \
    _Pragma("unroll") for (int ks = 0; ks < 4; ks++) {                         \
      long af[4], bfr[4];                                                      \
      _Pragma("unroll") for (int mf = 0; mf < 4; mf++) af[mf] =                \
          *(const long*)&As[BUF][mh * 64 + mf * 16 + lo4]                      \
                            [((ks * 4 + g) ^ lo4) * 8];                        \
      _Pragma("unroll") for (int cf = 0; cf < 4; cf++) bfr[cf] =               \
          *(const long*)&Bs[BUF][ch * 64 + cf * 16 + lo4]                      \
                            [((ks * 4 + g) ^ lo4) * 8];                        \
      _Pragma("unroll") for (int mf = 0; mf < 4; mf++)                         \
          _Pragma("unroll") for (int cf = 0; cf < 4; cf++) acc[mf][cf] =       \
              MFMA8(af[mf], bfr[cf], acc[mf][cf]);                             \
    }                                                                          \
  }
  LOADSET(eA, eB, 0);
  STORE_TILE(0, eA, eB);
  LOADSET(oA, oB, 1);
  __syncthreads();
  for (int tt2 = 0; tt2 < 16; tt2 += 2) {
    if (tt2 + 2 < 16) LOADSET(eA, eB, tt2 + 2);
    FRAGS_MFMA(0);
    STORE_TILE(1, oA, oB);
    __syncthreads();
    if (tt2 + 3 < 16) LOADSET(oA, oB, tt2 + 3);
    FRAGS_MFMA(1);
    if (tt2 + 2 < 16) STORE_TILE(0, eA, eB);
    __syncthreads();
  }
#undef FRAGS_MFMA
#undef STORE_TILE
#undef LOADSET
  // epilogue: h = x - 2^-8 * acc; per-wave LDS transpose -> hT[m][c]
  bf16* bncw = ((bf16*)As) + w * 16 * 72;
#pragma unroll
  for (int mf = 0; mf < 4; mf++) {
    const int mbase = m0 + mh * 64 + mf * 16;
    float hh[4][4];
#pragma unroll
    for (int cf = 0; cf < 4; cf++) {
      const int c = c0 + ch * 64 + cf * 16 + lo4;
      const f32x4 xval =
          *(const f32x4*)&x[((size_t)(b * kC + c)) * kN + mbase + g * 4];
#pragma unroll
      for (int r = 0; r < 4; r++)
        hh[cf][r] = xval[r] - acc[mf][cf][r] * 0.00390625f;
    }
#pragma unroll
    for (int cf = 0; cf < 4; cf++)
#pragma unroll
      for (int r = 0; r < 4; r++)
        bncw[(4 * g + r) * 72 + cf * 16 + lo4] = (bf16)hh[cf][r];
    {
      const int rr = l >> 2, seg = (l & 3) * 16;
      const bf16x8 v0 = *(const bf16x8*)&bncw[rr * 72 + seg];
      const bf16x8 v1 = *(const bf16x8*)&bncw[rr * 72 + seg + 8];
      bf16* orow =
          &hT[((size_t)(b * kN + mbase + rr)) * kC + c0 + ch * 64 + seg];
      *(bf16x8*)&orow[0] = v0;
      *(bf16x8*)&orow[8] = v1;
    }
  }
}

// -------- final: D[n][c] = hT[n][k] wt[c][k]; BN+ReLU+residual
__global__ __launch_bounds__(256, 2) void k_final(
    const bf16* __restrict__ hT, const bf16* __restrict__ wt_bf,
    const float* __restrict__ x, const float* __restrict__ bt,
    const float* __restrict__ beta, const float* __restrict__ rmean,
    const float* __restrict__ invg, float* __restrict__ out) {
  __shared__ __align__(16) bf16 As[2][128][32];
  __shared__ __align__(16) bf16 Bs[2][128][32];
  const int blk = blockIdx.x;  // 512 = 8b x (16nb x 4cb)
  const int b = blk & 7, tile = blk >> 3;
  const int cb = tile & 3, nb = tile >> 2;
  const int n0 = nb * 128, c0 = cb * 128;
  const int t_ = threadIdx.x, w = t_ >> 6, l = t_ & 63, lo4 = l & 15, g = l >> 4;
  const int mh = w >> 1, ch = w & 1;
  const int srow = w * 16 + (l >> 2), sch = l & 3;
  const int spos = sch ^ ((l >> 3) & 3);
  const int rpos = g ^ ((lo4 >> 1) & 3);
  const bf16* gA0 = &hT[((size_t)(b * kN + n0 + srow)) * kC + sch * 8];
  const bf16* gA1 = gA0 + (size_t)64 * kC;
  const bf16* gB0 = &wt_bf[(size_t)(c0 + srow) * kC + sch * 8];
  const bf16* gB1 = gB0 + (size_t)64 * kC;
  f32x4 acc[4][4] = {};
  bf16x8 ra0, ra1, rb0, rb1;
  ra0 = *(const bf16x8*)&gA0[0];
  ra1 = *(const bf16x8*)&gA1[0];
  rb0 = *(const bf16x8*)&gB0[0];
  rb1 = *(const bf16x8*)&gB1[0];
  *(bf16x8*)&As[0][srow][spos * 8] = ra0;
  *(bf16x8*)&As[0][srow + 64][spos * 8] = ra1;
  *(bf16x8*)&Bs[0][srow][spos * 8] = rb0;
  *(bf16x8*)&Bs[0][srow + 64][spos * 8] = rb1;
  __syncthreads();
  for (int tt = 0; tt < 16; tt++) {
    const int buf = tt & 1;
    if (tt < 15) {
      const int k0 = (tt + 1) * 32;
      ra0 = *(const bf16x8*)&gA0[k0];
      ra1 = *(const bf16x8*)&gA1[k0];
      rb0 = *(const bf16x8*)&gB0[k0];
      rb1 = *(const bf16x8*)&gB1[k0];
    }
    bf16x8 af[4], bfr[4];
#pragma unroll
    for (int nf = 0; nf < 4; nf++)
      af[nf] = *(const bf16x8*)&As[buf][mh * 64 + nf * 16 + lo4][rpos * 8];
#pragma unroll
    for (int cf = 0; cf < 4; cf++)
      bfr[cf] = *(const bf16x8*)&Bs[buf][ch * 64 + cf * 16 + lo4][rpos * 8];
#pragma unroll
    for (int nf = 0; nf < 4; nf++)
#pragma unroll
      for (int cf = 0; cf < 4; cf++)
        acc[nf][cf] = MFMA16(af[nf], bfr[cf], acc[nf][cf]);
    if (tt < 15) {
      *(bf16x8*)&As[buf ^ 1][srow][spos * 8] = ra0;
      *(bf16x8*)&As[buf ^ 1][srow + 64][spos * 8] = ra1;
      *(bf16x8*)&Bs[buf ^ 1][srow][spos * 8] = rb0;
      *(bf16x8*)&Bs[buf ^ 1][srow + 64][spos * 8] = rb1;
    }
    __syncthreads();
  }
#pragma unroll
  for (int cf = 0; cf < 4; cf++) {
    const int c = c0 + ch * 64 + cf * 16 + lo4;
    const float btv = bt[c], rmv = rmean[c], igv = invg[c], bev = beta[c];
#pragma unroll
    for (int nf = 0; nf < 4; nf++) {
      const int nbase = n0 + mh * 64 + nf * 16 + g * 4;
      const size_t base = ((size_t)(b * kC + c)) * kN + nbase;
      const f32x4 xval = *(const f32x4*)&x[base];
      f32x4 o;
#pragma unroll
      for (int r = 0; r < 4; r++) {
        float v = (acc[nf][cf][r] + btv - rmv) * igv + bev;
        v = fmaxf(v, 0.0f);
        o[r] = xval[r] + v;
      }
      *(f32x4*)&out[base] = o;
    }
  }
}

extern "C" void kernel_launch(void* const* d_in, const int* in_sizes, int n_in,
                              void* d_out, int out_size, void* d_ws,
                              size_t ws_size, hipStream_t stream) {
  const float* x = (const float*)d_in[0];
  const float* query = (const float*)d_in[1];
  const int* mask = (const int*)d_in[2];
  const float* wqk = (const float*)d_in[3];
  const float* wv = (const float*)d_in[4];
  const float* bv = (const float*)d_in[5];
  const float* wt = (const float*)d_in[6];
  const float* bt = (const float*)d_in[7];
  const float* gamma = (const float*)d_in[8];
  const float* beta = (const float*)d_in[9];
  const float* rmean = (const float*)d_in[10];
  const float* rvar = (const float*)d_in[11];
  float* out = (float*)d_out;
  char* wsb = (char*)d_ws;

  const size_t MB = 1024 * 1024;
  unsigned char* UT8 = (unsigned char*)wsb;      // 32 MB [b][m][n] fp8
  unsigned char* xv8 = (unsigned char*)(wsb + 32 * MB);  // 8 MB fp8 tiled
  bf16* hT = (bf16*)(wsb + 40 * MB);             // 8 MB [b][n][c]
  unsigned char* qT8 = (unsigned char*)(wsb + 48 * MB);  // 2 MB
  unsigned char* kT8 = (unsigned char*)(wsb + 50 * MB);  // 2 MB
  bf16* trbufQ = (bf16*)(wsb + 52 * MB);         // 16 MB
  bf16* trbufX = (bf16*)(wsb + 68 * MB);         // 16 MB
  bf16* wqk_bf = (bf16*)(wsb + 84 * MB);         // 128 KB
  bf16* wv_bf = wqk_bf + 65536;                  // 512 KB
  bf16* wt_bf = wv_bf + 262144;                  // 512 KB
  float* invg = (float*)(wt_bf + 262144);        // 2 KB
  float* Ssum = invg + 512;                      // 64 KB
  float* cnt = Ssum + kB * kN;                   // 32 B

  k_prep<<<136, 256, 0, stream>>>(mask, wqk, wv, wt, gamma, rvar, cnt, wqk_bf,
                                  wv_bf, wt_bf, invg, Ssum);
  k_tr2<<<dim3(kN / 64, kC / 32, 16), 256, 0, stream>>>(query, x, trbufQ,
                                                        trbufX);
  k_projQK<<<dim3(16, kB, 2), 256, 0, stream>>>(trbufQ, trbufX, wqk_bf, qT8,
                                                kT8);
  k_sum<<<512, 256, 0, stream>>>(qT8, kT8, mask, cnt, UT8, Ssum);
  k_projV<<<512, 256, 0, stream>>>(trbufX, wv_bf, bv, Ssum, xv8);
  k_attn2<<<512, 256, 0, stream>>>(UT8, xv8, x, hT);
  k_final<<<512, 256, 0, stream>>>(hT, wt_bf, x, bt, beta, rmean, invg, out);
}